// Round 2
// baseline (1520.955 us; speedup 1.0000x reference)
//
#include <hip/hip_runtime.h>
#include <hip/hip_bf16.h>
#include <math.h>

#define NNODES 50000
#define NEDGES 400000
#define ETOT   (NEDGES + NNODES)   // edges + self-loops
#define NGRAPHS 64

__device__ __forceinline__ float lrelu(float x){ return x >= 0.f ? x : 0.2f*x; }
__device__ __forceinline__ float eluf(float x){ return x > 0.f ? x : expm1f(x); }
__device__ __forceinline__ unsigned fenc(float f){ unsigned u=__float_as_uint(f); return (u&0x80000000u)? ~u : (u|0x80000000u); }
__device__ __forceinline__ float fdec(unsigned u){ return __uint_as_float((u&0x80000000u)? (u^0x80000000u) : ~u); }
__device__ __forceinline__ float blo(unsigned w){ return __uint_as_float(w<<16); }
__device__ __forceinline__ float bhi(unsigned w){ return __uint_as_float(w & 0xffff0000u); }

// ---------------- CSR build (self-loop at slot 0 of each row) ----------------
__global__ void k_one(int* __restrict__ deg){
  int i = blockIdx.x*256 + threadIdx.x;
  if (i < NNODES) deg[i] = 1;
}
__global__ void k_hist(const int* __restrict__ ei, int* __restrict__ deg){
  int e = blockIdx.x*blockDim.x + threadIdx.x;
  if (e < NEDGES) atomicAdd(&deg[ei[NEDGES + e]], 1);
}
__global__ void k_scan1(const int* __restrict__ deg, int* __restrict__ part, int n){
  __shared__ int buf[256];
  int i = blockIdx.x*256 + threadIdx.x;
  buf[threadIdx.x] = (i<n)? deg[i] : 0;
  __syncthreads();
  for (int s=128; s>0; s>>=1){ if (threadIdx.x < s) buf[threadIdx.x]+=buf[threadIdx.x+s]; __syncthreads(); }
  if (threadIdx.x==0) part[blockIdx.x]=buf[0];
}
__global__ void k_scan2(const int* __restrict__ part, int* __restrict__ bpre, int* __restrict__ row_off_last, int nb){
  __shared__ int buf[256];
  int t = threadIdx.x;
  int v = (t<nb)? part[t] : 0;
  buf[t]=v; __syncthreads();
  for (int s=1;s<256;s<<=1){ int a = (t>=s)? buf[t-s]:0; __syncthreads(); buf[t]+=a; __syncthreads(); }
  if (t<nb) bpre[t] = buf[t]-v;
  if (t==255) row_off_last[0] = buf[255];
}
__global__ void k_scan3(const int* __restrict__ deg, const int* __restrict__ bpre, int* __restrict__ row_off, int n){
  __shared__ int buf[256];
  int t = threadIdx.x;
  int i = blockIdx.x*256 + t;
  int v = (i<n)? deg[i]:0;
  buf[t]=v; __syncthreads();
  for (int s=1;s<256;s<<=1){ int a=(t>=s)?buf[t-s]:0; __syncthreads(); buf[t]+=a; __syncthreads(); }
  if (i<n) row_off[i] = bpre[blockIdx.x] + buf[t]-v;
}
__global__ void k_selfpos(const int* __restrict__ row_off, int* __restrict__ csr_src,
                          int* __restrict__ csr_dst, int* __restrict__ cursor){
  int n = blockIdx.x*256 + threadIdx.x;
  if (n < NNODES){
    int p = row_off[n];
    csr_src[p] = n; csr_dst[p] = n;
    cursor[n] = 1;
  }
}
__global__ void k_scatter(const int* __restrict__ ei, const int* __restrict__ row_off,
                          int* __restrict__ cursor, int* __restrict__ csr_src, int* __restrict__ csr_dst){
  int e = blockIdx.x*blockDim.x + threadIdx.x;
  if (e < NEDGES){
    int s = ei[e], d = ei[NEDGES+e];
    int pos = row_off[d] + atomicAdd(&cursor[d],1);
    csr_src[pos] = s; csr_dst[pos] = d;
  }
}

// ---------------- generic f32 GEMM (layer1): C = A[M,K] @ W[K,N] ----------------
__global__ __launch_bounds__(256) void k_gemm(const float* __restrict__ A, const float* __restrict__ W,
                                              float* __restrict__ Cmat, int M, int K, int N){
  __shared__ __align__(16) float As[16][128];
  __shared__ __align__(16) float Bs[16][64];
  int tid = threadIdx.x;
  int tx = tid & 15, ty = tid >> 4;
  int n0 = blockIdx.x * 64;
  int m0 = blockIdx.y * 128;
  int a_row = tid >> 1, a_k = (tid & 1)*8;
  int b_k = tid >> 4, b_n = (tid & 15)*4;
  float acc[8][4];
  #pragma unroll
  for (int i=0;i<8;i++)
    #pragma unroll
    for (int j=0;j<4;j++) acc[i][j]=0.f;
  for (int k0=0;k0<K;k0+=16){
    int grow = m0 + a_row;
    float4 va = make_float4(0.f,0.f,0.f,0.f), vb = va;
    if (grow < M){
      const float* p = &A[(size_t)grow*K + k0 + a_k];
      va = *(const float4*)p; vb = *(const float4*)(p+4);
    }
    float4 w = *(const float4*)&W[(size_t)(k0+b_k)*N + n0 + b_n];
    __syncthreads();
    As[a_k+0][a_row]=va.x; As[a_k+1][a_row]=va.y; As[a_k+2][a_row]=va.z; As[a_k+3][a_row]=va.w;
    As[a_k+4][a_row]=vb.x; As[a_k+5][a_row]=vb.y; As[a_k+6][a_row]=vb.z; As[a_k+7][a_row]=vb.w;
    *(float4*)&Bs[b_k][b_n] = w;
    __syncthreads();
    #pragma unroll
    for (int kk=0;kk<16;kk++){
      float4 a0 = *(const float4*)&As[kk][ty*8];
      float4 a1 = *(const float4*)&As[kk][ty*8+4];
      float4 b  = *(const float4*)&Bs[kk][tx*4];
      float av[8] = {a0.x,a0.y,a0.z,a0.w,a1.x,a1.y,a1.z,a1.w};
      float bv[4] = {b.x,b.y,b.z,b.w};
      #pragma unroll
      for (int i=0;i<8;i++)
        #pragma unroll
        for (int j=0;j<4;j++) acc[i][j] = fmaf(av[i], bv[j], acc[i][j]);
    }
  }
  #pragma unroll
  for (int i=0;i<8;i++){
    int row = m0 + ty*8 + i;
    if (row < M){
      float4 o = make_float4(acc[i][0],acc[i][1],acc[i][2],acc[i][3]);
      *(float4*)&Cmat[(size_t)row*N + n0 + tx*4] = o;
    }
  }
}

// ---------------- layer1 scores (from h1 directly) + m/den init ----------------
template<int C>
__global__ void k_scores(const float* __restrict__ h, const float* __restrict__ as_,
                         const float* __restrict__ ad_, float* __restrict__ es, float* __restrict__ ed,
                         unsigned* __restrict__ mEnc, float* __restrict__ den){
  constexpr int HC = 4*C;
  __shared__ float ls[HC];
  __shared__ float ld2[HC];
  int n = blockIdx.x, t = threadIdx.x;
  float v = h[(size_t)n*HC + t];
  ls[t] = v * as_[t]; ld2[t] = v * ad_[t];
  __syncthreads();
  int cc = t & (C-1);
  for (int s=C/2; s>0; s>>=1){
    if (cc < s){ ls[t]+=ls[t+s]; ld2[t]+=ld2[t+s]; }
    __syncthreads();
  }
  if (cc==0){ int hd = t / C; es[n*4+hd]=ls[t]; ed[n*4+hd]=ld2[t]; }
  if (t < 4){ mEnc[n*4+t] = fenc(-INFINITY); den[n*4+t] = 0.f; }
}

// ---------------- head projections P[k][0..3]=W_h@as_h, P[k][4..7]=W_h@ad_h ----------------
template<int KF,int C>
__global__ void k_proj(const float* __restrict__ W, const float* __restrict__ as_,
                       const float* __restrict__ ad_, float* __restrict__ P){
  int u = blockIdx.x*256 + threadIdx.x;
  if (u >= KF*8) return;
  int k = u>>3, o = u&7; int h = o&3;
  const float* a = (o<4? as_ : ad_) + h*C;
  const float* w = W + (size_t)k*(4*C) + h*C;
  float s=0.f;
  for (int c=0;c<C;c++) s = fmaf(w[c], a[c], s);
  P[k*8+o]=s;
}

// ---------------- scores via projection: es/ed = g @ P ----------------
template<int KF>
__global__ void k_scores_lin(const float* __restrict__ g, const float* __restrict__ P,
                             float* __restrict__ es, float* __restrict__ ed,
                             unsigned* __restrict__ mEnc, float* __restrict__ den){
  int n = blockIdx.x*4 + (threadIdx.x>>6);
  int lane = threadIdx.x & 63;
  if (n >= NNODES) return;
  constexpr int NI = KF/64;
  float v[NI];
  #pragma unroll
  for (int i=0;i<NI;i++) v[i] = g[(size_t)n*KF + i*64 + lane];
  #pragma unroll
  for (int o=0;o<8;o++){
    float p=0.f;
    #pragma unroll
    for (int i=0;i<NI;i++) p = fmaf(v[i], P[(i*64+lane)*8 + o], p);
    #pragma unroll
    for (int m=32;m>0;m>>=1) p += __shfl_xor(p, m, 64);
    if (lane==0){ if (o<4) es[n*4+o]=p; else ed[n*4+(o-4)]=p; }
  }
  if (lane<4){ mEnc[n*4+lane]=fenc(-INFINITY); den[n*4+lane]=0.f; }
}

// ---------------- edge-parallel max / alpha ----------------
__global__ void k_max(const int* __restrict__ csr_src, const int* __restrict__ csr_dst,
                      const float* __restrict__ es, const float* __restrict__ ed,
                      unsigned* __restrict__ mEnc){
  int p = blockIdx.x*256 + threadIdx.x;
  if (p >= ETOT) return;
  int s = csr_src[p], d = csr_dst[p];
  float4 a = *(const float4*)&es[s*4];
  float4 b = *(const float4*)&ed[d*4];
  atomicMax(&mEnc[d*4+0], fenc(lrelu(a.x+b.x)));
  atomicMax(&mEnc[d*4+1], fenc(lrelu(a.y+b.y)));
  atomicMax(&mEnc[d*4+2], fenc(lrelu(a.z+b.z)));
  atomicMax(&mEnc[d*4+3], fenc(lrelu(a.w+b.w)));
}
__global__ void k_alpha(const int* __restrict__ csr_src, const int* __restrict__ csr_dst,
                        const float* __restrict__ es, const float* __restrict__ ed,
                        const unsigned* __restrict__ mEnc, float* __restrict__ alphaN,
                        float* __restrict__ den){
  int p = blockIdx.x*256 + threadIdx.x;
  if (p >= ETOT) return;
  int s = csr_src[p], d = csr_dst[p];
  float4 a = *(const float4*)&es[s*4];
  float4 b = *(const float4*)&ed[d*4];
  uint4 m = *(const uint4*)&mEnc[d*4];
  float4 r;
  r.x = expf(lrelu(a.x+b.x) - fdec(m.x));
  r.y = expf(lrelu(a.y+b.y) - fdec(m.y));
  r.z = expf(lrelu(a.z+b.z) - fdec(m.z));
  r.w = expf(lrelu(a.w+b.w) - fdec(m.w));
  *(float4*)&alphaN[(size_t)p*4] = r;
  atomicAdd(&den[d*4+0], r.x);
  atomicAdd(&den[d*4+1], r.y);
  atomicAdd(&den[d*4+2], r.z);
  atomicAdd(&den[d*4+3], r.w);
}

// ---------------- layer1 aggregation (gathers h1, 64 feat) + bias + ELU ----------------
__global__ void k_gat1(const float* __restrict__ h1, const float* __restrict__ alphaN,
                       const int* __restrict__ row_off, const int* __restrict__ csr_src,
                       const float* __restrict__ den, const float* __restrict__ b1,
                       float* __restrict__ g1){
  int n = blockIdx.x*4 + (threadIdx.x>>6);
  if (n >= NNODES) return;
  int t = threadIdx.x & 63;
  int head = t >> 4;
  int pos = row_off[n], end = row_off[n+1];
  float acc = 0.f;
  for (; pos+1 < end; pos += 2){
    int s0 = csr_src[pos], s1 = csr_src[pos+1];
    float a0 = alphaN[(size_t)pos*4 + head];
    float a1 = alphaN[(size_t)(pos+1)*4 + head];
    float v0 = h1[(size_t)s0*64 + t];
    float v1 = h1[(size_t)s1*64 + t];
    acc = fmaf(a0, v0, acc);
    acc = fmaf(a1, v1, acc);
  }
  if (pos < end){
    int s0 = csr_src[pos];
    acc = fmaf(alphaN[(size_t)pos*4 + head], h1[(size_t)s0*64 + t], acc);
  }
  float r = acc / (den[n*4+head] + 1e-16f);
  g1[(size_t)n*64 + t] = eluf(r + b1[t]);
}

// ---------------- layer2 aggregation of g1 (64 feat) with 4 head alphas ----------------
__global__ void k_gat_agg2(const float* __restrict__ g1, const float* __restrict__ alphaN,
                           const int* __restrict__ row_off, const int* __restrict__ csr_src,
                           const float* __restrict__ den, float* __restrict__ agg){
  int n = blockIdx.x*4 + (threadIdx.x>>6);
  if (n >= NNODES) return;
  int t = threadIdx.x & 63;
  int pos = row_off[n], end = row_off[n+1];
  float c0=0.f,c1=0.f,c2=0.f,c3=0.f;
  for (; pos+1 < end; pos += 2){
    int s0 = csr_src[pos], s1 = csr_src[pos+1];
    float4 a0 = *(const float4*)&alphaN[(size_t)pos*4];
    float4 a1 = *(const float4*)&alphaN[(size_t)(pos+1)*4];
    float v0 = g1[(size_t)s0*64 + t];
    float v1 = g1[(size_t)s1*64 + t];
    c0=fmaf(a0.x,v0,c0); c1=fmaf(a0.y,v0,c1); c2=fmaf(a0.z,v0,c2); c3=fmaf(a0.w,v0,c3);
    c0=fmaf(a1.x,v1,c0); c1=fmaf(a1.y,v1,c1); c2=fmaf(a1.z,v1,c2); c3=fmaf(a1.w,v1,c3);
  }
  if (pos < end){
    int s0 = csr_src[pos];
    float4 a0 = *(const float4*)&alphaN[(size_t)pos*4];
    float v0 = g1[(size_t)s0*64 + t];
    c0=fmaf(a0.x,v0,c0); c1=fmaf(a0.y,v0,c1); c2=fmaf(a0.z,v0,c2); c3=fmaf(a0.w,v0,c3);
  }
  float4 dn = *(const float4*)&den[n*4];
  size_t base = (size_t)n*256;
  agg[base +       t] = c0/(dn.x+1e-16f);
  agg[base +  64 + t] = c1/(dn.y+1e-16f);
  agg[base + 128 + t] = c2/(dn.z+1e-16f);
  agg[base + 192 + t] = c3/(dn.w+1e-16f);
}

// ---------------- layer3 aggregation of g2 (256 feat), bf16 output ----------------
__global__ __launch_bounds__(256) void k_gat_agg3(const float* __restrict__ g2, const float* __restrict__ alphaN,
                           const int* __restrict__ row_off, const int* __restrict__ csr_src,
                           const float* __restrict__ den, __hip_bfloat16* __restrict__ agg){
  int n = blockIdx.x;
  int t = threadIdx.x;
  int pos = row_off[n], end = row_off[n+1];
  float c0=0.f,c1=0.f,c2=0.f,c3=0.f;
  for (; pos+1 < end; pos += 2){
    int s0 = csr_src[pos], s1 = csr_src[pos+1];
    float4 a0 = *(const float4*)&alphaN[(size_t)pos*4];
    float4 a1 = *(const float4*)&alphaN[(size_t)(pos+1)*4];
    float v0 = g2[(size_t)s0*256 + t];
    float v1 = g2[(size_t)s1*256 + t];
    c0=fmaf(a0.x,v0,c0); c1=fmaf(a0.y,v0,c1); c2=fmaf(a0.z,v0,c2); c3=fmaf(a0.w,v0,c3);
    c0=fmaf(a1.x,v1,c0); c1=fmaf(a1.y,v1,c1); c2=fmaf(a1.z,v1,c2); c3=fmaf(a1.w,v1,c3);
  }
  if (pos < end){
    int s0 = csr_src[pos];
    float4 a0 = *(const float4*)&alphaN[(size_t)pos*4];
    float v0 = g2[(size_t)s0*256 + t];
    c0=fmaf(a0.x,v0,c0); c1=fmaf(a0.y,v0,c1); c2=fmaf(a0.z,v0,c2); c3=fmaf(a0.w,v0,c3);
  }
  float4 dn = *(const float4*)&den[n*4];
  size_t base = (size_t)n*1024;
  agg[base +       t] = __float2bfloat16(c0/(dn.x+1e-16f));
  agg[base + 256 + t] = __float2bfloat16(c1/(dn.y+1e-16f));
  agg[base + 512 + t] = __float2bfloat16(c2/(dn.z+1e-16f));
  agg[base + 768 + t] = __float2bfloat16(c3/(dn.w+1e-16f));
}

// ---------------- layer2 per-head GEMM: g2[:,h*64+..] = ELU(agg2_h @ W2_h + b2) ----------------
__global__ __launch_bounds__(256) void k_gemm_l2(const float* __restrict__ A, const float* __restrict__ W2,
                                                 const float* __restrict__ b2, float* __restrict__ g2){
  __shared__ __align__(16) float As[16][128];
  __shared__ __align__(16) float Bs[16][64];
  int tid = threadIdx.x;
  int h = blockIdx.x;
  int tx = tid & 15, ty = tid >> 4;
  int m0 = blockIdx.y * 128;
  int a_row = tid >> 1, a_k = (tid & 1)*8;
  int b_k = tid >> 4, b_n = (tid & 15)*4;
  float acc[8][4];
  #pragma unroll
  for (int i=0;i<8;i++)
    #pragma unroll
    for (int j=0;j<4;j++) acc[i][j]=0.f;
  for (int k0=0;k0<64;k0+=16){
    int grow = m0 + a_row;
    float4 va = make_float4(0.f,0.f,0.f,0.f), vb = va;
    if (grow < NNODES){
      const float* p = &A[(size_t)grow*256 + h*64 + k0 + a_k];
      va = *(const float4*)p; vb = *(const float4*)(p+4);
    }
    float4 w = *(const float4*)&W2[(size_t)(k0+b_k)*256 + h*64 + b_n];
    __syncthreads();
    As[a_k+0][a_row]=va.x; As[a_k+1][a_row]=va.y; As[a_k+2][a_row]=va.z; As[a_k+3][a_row]=va.w;
    As[a_k+4][a_row]=vb.x; As[a_k+5][a_row]=vb.y; As[a_k+6][a_row]=vb.z; As[a_k+7][a_row]=vb.w;
    *(float4*)&Bs[b_k][b_n] = w;
    __syncthreads();
    #pragma unroll
    for (int kk=0;kk<16;kk++){
      float4 a0 = *(const float4*)&As[kk][ty*8];
      float4 a1 = *(const float4*)&As[kk][ty*8+4];
      float4 b  = *(const float4*)&Bs[kk][tx*4];
      float av[8] = {a0.x,a0.y,a0.z,a0.w,a1.x,a1.y,a1.z,a1.w};
      float bv[4] = {b.x,b.y,b.z,b.w};
      #pragma unroll
      for (int i=0;i<8;i++)
        #pragma unroll
        for (int j=0;j<4;j++) acc[i][j] = fmaf(av[i], bv[j], acc[i][j]);
    }
  }
  #pragma unroll
  for (int i=0;i<8;i++){
    int row = m0 + ty*8 + i;
    if (row < NNODES){
      int col = h*64 + tx*4;
      float4 o;
      o.x = eluf(acc[i][0] + b2[col+0]);
      o.y = eluf(acc[i][1] + b2[col+1]);
      o.z = eluf(acc[i][2] + b2[col+2]);
      o.w = eluf(acc[i][3] + b2[col+3]);
      *(float4*)&g2[(size_t)row*256 + col] = o;
    }
  }
}

// ---------------- layer3 GEMM (bf16 A, head-mean + bias + ELU epilogue) ----------------
__global__ __launch_bounds__(256) void k_gemm_l3(const __hip_bfloat16* __restrict__ A,
                                                 const float* __restrict__ W3, const float* __restrict__ b3,
                                                 float* __restrict__ g3){
  __shared__ __align__(16) float As[16][128];
  __shared__ __align__(16) float Bs[16][128];
  int tid = threadIdx.x;
  int tx = tid & 15, ty = tid >> 4;
  int m0 = blockIdx.y * 128;
  int a_row = tid >> 1, a_k = (tid & 1)*8;
  int b_k = tid >> 4, b_n = (tid & 15)*8;
  float acc[8][8];
  #pragma unroll
  for (int i=0;i<8;i++)
    #pragma unroll
    for (int j=0;j<8;j++) acc[i][j]=0.f;
  for (int h=0; h<4; ++h){
    for (int k0=0; k0<256; k0+=16){
      int grow = m0 + a_row;
      uint4 ar = make_uint4(0u,0u,0u,0u);
      if (grow < NNODES)
        ar = *(const uint4*)&A[(size_t)grow*1024 + h*256 + k0 + a_k];
      float4 w0 = *(const float4*)&W3[(size_t)(k0+b_k)*512 + h*128 + b_n];
      float4 w1 = *(const float4*)&W3[(size_t)(k0+b_k)*512 + h*128 + b_n + 4];
      __syncthreads();
      As[a_k+0][a_row]=blo(ar.x); As[a_k+1][a_row]=bhi(ar.x);
      As[a_k+2][a_row]=blo(ar.y); As[a_k+3][a_row]=bhi(ar.y);
      As[a_k+4][a_row]=blo(ar.z); As[a_k+5][a_row]=bhi(ar.z);
      As[a_k+6][a_row]=blo(ar.w); As[a_k+7][a_row]=bhi(ar.w);
      *(float4*)&Bs[b_k][b_n] = w0;
      *(float4*)&Bs[b_k][b_n+4] = w1;
      __syncthreads();
      #pragma unroll
      for (int kk=0;kk<16;kk++){
        float4 x0 = *(const float4*)&As[kk][ty*8];
        float4 x1 = *(const float4*)&As[kk][ty*8+4];
        float4 y0 = *(const float4*)&Bs[kk][tx*8];
        float4 y1 = *(const float4*)&Bs[kk][tx*8+4];
        float xv[8] = {x0.x,x0.y,x0.z,x0.w,x1.x,x1.y,x1.z,x1.w};
        float yv[8] = {y0.x,y0.y,y0.z,y0.w,y1.x,y1.y,y1.z,y1.w};
        #pragma unroll
        for (int i=0;i<8;i++)
          #pragma unroll
          for (int j=0;j<8;j++) acc[i][j] = fmaf(xv[i], yv[j], acc[i][j]);
      }
    }
  }
  #pragma unroll
  for (int i=0;i<8;i++){
    int row = m0 + ty*8 + i;
    if (row < NNODES){
      int col = tx*8;
      float4 o0, o1;
      o0.x = eluf(0.25f*acc[i][0] + b3[col+0]);
      o0.y = eluf(0.25f*acc[i][1] + b3[col+1]);
      o0.z = eluf(0.25f*acc[i][2] + b3[col+2]);
      o0.w = eluf(0.25f*acc[i][3] + b3[col+3]);
      o1.x = eluf(0.25f*acc[i][4] + b3[col+4]);
      o1.y = eluf(0.25f*acc[i][5] + b3[col+5]);
      o1.z = eluf(0.25f*acc[i][6] + b3[col+6]);
      o1.w = eluf(0.25f*acc[i][7] + b3[col+7]);
      *(float4*)&g3[(size_t)row*128 + col] = o0;
      *(float4*)&g3[(size_t)row*128 + col + 4] = o1;
    }
  }
}

// ---------------- pooling + linear head ----------------
__device__ __forceinline__ int lowerb(const int* a, int n, int v){
  int lo=0, hi=n;
  while (lo<hi){ int mid=(lo+hi)>>1; if (a[mid]<v) lo=mid+1; else hi=mid; }
  return lo;
}
__global__ void k_pool(const float* __restrict__ g3, const int* __restrict__ batch, float* __restrict__ pooled){
  int g = blockIdx.x, c = threadIdx.x; // 64 blocks x 128 threads
  int lo = lowerb(batch, NNODES, g);
  int hi = lowerb(batch, NNODES, g+1);
  float s = 0.f;
  for (int nn=lo; nn<hi; ++nn) s += g3[(size_t)nn*128 + c];
  int cnt = hi-lo;
  pooled[g*128+c] = s / fmaxf((float)cnt, 1.f);
}
__global__ void k_lin(const float* __restrict__ pooled, const float* __restrict__ Wlin,
                      const float* __restrict__ blin, float* __restrict__ out){
  int t = threadIdx.x;
  if (t < 640){
    int g = t/10, j = t%10;
    float s = blin[j];
    for (int c=0;c<128;c++) s = fmaf(pooled[g*128+c], Wlin[c*10+j], s);
    out[t] = s;
  }
}

extern "C" void kernel_launch(void* const* d_in, const int* in_sizes, int n_in,
                              void* d_out, int out_size, void* d_ws, size_t ws_size,
                              hipStream_t stream){
  (void)in_sizes; (void)n_in; (void)out_size; (void)ws_size;
  const float* x    = (const float*)d_in[0];
  const int*   ei   = (const int*)d_in[1];
  const int*   batch= (const int*)d_in[2];
  const float* W1   = (const float*)d_in[3];
  const float* as1  = (const float*)d_in[4];
  const float* ad1  = (const float*)d_in[5];
  const float* b1   = (const float*)d_in[6];
  const float* W2   = (const float*)d_in[7];
  const float* as2  = (const float*)d_in[8];
  const float* ad2  = (const float*)d_in[9];
  const float* b2   = (const float*)d_in[10];
  const float* W3   = (const float*)d_in[11];
  const float* as3  = (const float*)d_in[12];
  const float* ad3  = (const float*)d_in[13];
  const float* b3   = (const float*)d_in[14];
  const float* Wlin = (const float*)d_in[15];
  const float* blin = (const float*)d_in[16];
  float* out = (float*)d_out;

  char* ws = (char*)d_ws;
  size_t off = 0;
  auto alloc = [&](size_t bytes)->char*{ char* p = ws + off; off += (bytes + 255) & ~(size_t)255; return p; };
  // persistent small buffers
  int* csr_src = (int*)alloc((size_t)ETOT*4);
  int* csr_dst = (int*)alloc((size_t)ETOT*4);
  int* row_off = (int*)alloc((size_t)(NNODES+1)*4);
  int* deg     = (int*)alloc((size_t)NNODES*4);
  int* cursor  = (int*)alloc((size_t)NNODES*4);
  int* part    = (int*)alloc(256*4);
  int* bpre    = (int*)alloc(256*4);
  float* es    = (float*)alloc((size_t)NNODES*4*4);
  float* ed    = (float*)alloc((size_t)NNODES*4*4);
  unsigned* mEnc = (unsigned*)alloc((size_t)NNODES*4*4);
  float* den   = (float*)alloc((size_t)NNODES*4*4);
  float* alphaN= (float*)alloc((size_t)ETOT*4*4);
  float* P2    = (float*)alloc(64*8*4);
  float* P3    = (float*)alloc(256*8*4);
  float* pooled= (float*)alloc((size_t)NGRAPHS*128*4);
  // big slab X (102.4 MB): h1 | g1 | agg2 early, agg3(bf16) late
  char* X      = alloc((size_t)NNODES*1024*2);
  float* h1    = (float*)X;                          // 12.8 MB  [gemm1..gat1]
  float* g1    = (float*)(X + (size_t)12800000);     // 12.8 MB  [gat1..gat_agg2]
  float* agg2  = (float*)(X + (size_t)25600000);     // 51.2 MB  [gat_agg2..gemm_l2]
  __hip_bfloat16* agg3 = (__hip_bfloat16*)X;         // 102.4 MB [gat_agg3..gemm_l3]
  float* g2    = (float*)alloc((size_t)NNODES*256*4);  // 51.2 MB
  float* g3    = (float*)alloc((size_t)NNODES*128*4);  // 25.6 MB

  int nbE = (NEDGES+255)/256;
  int nbS = (NNODES+255)/256;
  int nbP = (ETOT+255)/256;
  int mb  = (NNODES+127)/128;

  // CSR with self-loops at slot 0
  k_one<<<nbS,256,0,stream>>>(deg);
  k_hist<<<nbE,256,0,stream>>>(ei, deg);
  k_scan1<<<nbS,256,0,stream>>>(deg, part, NNODES);
  k_scan2<<<1,256,0,stream>>>(part, bpre, row_off+NNODES, nbS);
  k_scan3<<<nbS,256,0,stream>>>(deg, bpre, row_off, NNODES);
  k_selfpos<<<nbS,256,0,stream>>>(row_off, csr_src, csr_dst, cursor);
  k_scatter<<<nbE,256,0,stream>>>(ei, row_off, cursor, csr_src, csr_dst);

  // ---- layer 1: x[*,128] @ W1 -> h1[*,64]; GAT on h1; out g1[*,64]
  k_gemm<<<dim3(1,mb),256,0,stream>>>(x, W1, h1, NNODES, 128, 64);
  k_scores<16><<<NNODES,64,0,stream>>>(h1, as1, ad1, es, ed, mEnc, den);
  k_max<<<nbP,256,0,stream>>>(csr_src, csr_dst, es, ed, mEnc);
  k_alpha<<<nbP,256,0,stream>>>(csr_src, csr_dst, es, ed, mEnc, alphaN, den);
  k_gat1<<<(NNODES+3)/4,256,0,stream>>>(h1, alphaN, row_off, csr_src, den, b1, g1);

  // ---- layer 2: aggregate g1 per head, then per-head GEMM with W2 (+b2, ELU) -> g2[*,256]
  k_proj<64,64><<<2,256,0,stream>>>(W2, as2, ad2, P2);
  k_scores_lin<64><<<(NNODES+3)/4,256,0,stream>>>(g1, P2, es, ed, mEnc, den);
  k_max<<<nbP,256,0,stream>>>(csr_src, csr_dst, es, ed, mEnc);
  k_alpha<<<nbP,256,0,stream>>>(csr_src, csr_dst, es, ed, mEnc, alphaN, den);
  k_gat_agg2<<<(NNODES+3)/4,256,0,stream>>>(g1, alphaN, row_off, csr_src, den, agg2);
  k_gemm_l2<<<dim3(4,mb),256,0,stream>>>(agg2, W2, b2, g2);

  // ---- layer 3: aggregate g2 per head (bf16), block-diag GEMM with W3, head-mean (+b3, ELU) -> g3[*,128]
  k_proj<256,128><<<8,256,0,stream>>>(W3, as3, ad3, P3);
  k_scores_lin<256><<<(NNODES+3)/4,256,0,stream>>>(g2, P3, es, ed, mEnc, den);
  k_max<<<nbP,256,0,stream>>>(csr_src, csr_dst, es, ed, mEnc);
  k_alpha<<<nbP,256,0,stream>>>(csr_src, csr_dst, es, ed, mEnc, alphaN, den);
  k_gat_agg3<<<NNODES,256,0,stream>>>(g2, alphaN, row_off, csr_src, den, agg3);
  k_gemm_l3<<<dim3(1,mb),256,0,stream>>>(agg3, W3, b3, g3);

  // ---- pool + linear
  k_pool<<<NGRAPHS,128,0,stream>>>(g3, batch, pooled);
  k_lin<<<1,1024,0,stream>>>(pooled, Wlin, blin, out);
}

// Round 3
// 707.517 us; speedup vs baseline: 2.1497x; 2.1497x over previous
//
#include <hip/hip_runtime.h>
#include <math.h>

#define NNODES 50000
#define NEDGES 400000
#define ETOT   (NEDGES + NNODES)
#define NGRAPHS 64

typedef _Float16 f16;
typedef _Float16 f16x4 __attribute__((ext_vector_type(4)));
typedef _Float16 f16x8 __attribute__((ext_vector_type(8)));
typedef float f32x4 __attribute__((ext_vector_type(4)));

__device__ __forceinline__ float lrelu(float x){ return x >= 0.f ? x : 0.2f*x; }
__device__ __forceinline__ float eluf(float x){ return x > 0.f ? x : expm1f(x); }

// ---------------- CSR build (self-loop at slot 0 of each row) ----------------
__global__ void k_one(int* __restrict__ deg){
  int i = blockIdx.x*256 + threadIdx.x;
  if (i < NNODES) deg[i] = 1;
}
__global__ void k_hist(const int* __restrict__ ei, int* __restrict__ deg){
  int e = blockIdx.x*blockDim.x + threadIdx.x;
  if (e < NEDGES) atomicAdd(&deg[ei[NEDGES + e]], 1);
}
__global__ void k_scan1(const int* __restrict__ deg, int* __restrict__ part, int n){
  __shared__ int buf[256];
  int i = blockIdx.x*256 + threadIdx.x;
  buf[threadIdx.x] = (i<n)? deg[i] : 0;
  __syncthreads();
  for (int s=128; s>0; s>>=1){ if (threadIdx.x < s) buf[threadIdx.x]+=buf[threadIdx.x+s]; __syncthreads(); }
  if (threadIdx.x==0) part[blockIdx.x]=buf[0];
}
__global__ void k_scan2(const int* __restrict__ part, int* __restrict__ bpre, int* __restrict__ row_off_last, int nb){
  __shared__ int buf[256];
  int t = threadIdx.x;
  int v = (t<nb)? part[t] : 0;
  buf[t]=v; __syncthreads();
  for (int s=1;s<256;s<<=1){ int a = (t>=s)? buf[t-s]:0; __syncthreads(); buf[t]+=a; __syncthreads(); }
  if (t<nb) bpre[t] = buf[t]-v;
  if (t==255) row_off_last[0] = buf[255];
}
__global__ void k_scan3(const int* __restrict__ deg, const int* __restrict__ bpre, int* __restrict__ row_off, int n){
  __shared__ int buf[256];
  int t = threadIdx.x;
  int i = blockIdx.x*256 + t;
  int v = (i<n)? deg[i]:0;
  buf[t]=v; __syncthreads();
  for (int s=1;s<256;s<<=1){ int a=(t>=s)?buf[t-s]:0; __syncthreads(); buf[t]+=a; __syncthreads(); }
  if (i<n) row_off[i] = bpre[blockIdx.x] + buf[t]-v;
}
__global__ void k_selfpos(const int* __restrict__ row_off, int* __restrict__ csr_src, int* __restrict__ cursor){
  int n = blockIdx.x*256 + threadIdx.x;
  if (n < NNODES){
    csr_src[row_off[n]] = n;
    cursor[n] = 1;
  }
}
__global__ void k_scatter(const int* __restrict__ ei, const int* __restrict__ row_off,
                          int* __restrict__ cursor, int* __restrict__ csr_src){
  int e = blockIdx.x*blockDim.x + threadIdx.x;
  if (e < NEDGES){
    int s = ei[e], d = ei[NEDGES+e];
    int pos = row_off[d] + atomicAdd(&cursor[d],1);
    csr_src[pos] = s;
  }
}

// ---------------- weight prep: BT1/BT2/BT3 (f16, col-major), P1/P2/P3 (f32) ----------------
__global__ void k_prep(const float* __restrict__ W1, const float* __restrict__ W2, const float* __restrict__ W3,
                       const float* __restrict__ as1, const float* __restrict__ ad1,
                       const float* __restrict__ as2, const float* __restrict__ ad2,
                       const float* __restrict__ as3, const float* __restrict__ ad3,
                       f16* __restrict__ BT1, f16* __restrict__ BT2, f16* __restrict__ BT3,
                       float* __restrict__ P1, float* __restrict__ P2, float* __restrict__ P3){
  int u = blockIdx.x*256 + threadIdx.x;
  if (u < 8192){ int j=u>>7, k=u&127; BT1[j*128+k] = (f16)W1[(size_t)k*64+j]; return; }
  u -= 8192;
  if (u < 16384){ int col=u>>6, k=u&63; BT2[col*64+k] = (f16)W2[(size_t)k*256+col]; return; }
  u -= 16384;
  if (u < 131072){ int j=u>>10, t=u&1023, h=t>>8, k=t&255;
                   BT3[(size_t)j*1024+t] = (f16)W3[(size_t)k*512 + h*128 + j]; return; }
  u -= 131072;
  if (u < 512){ int f=u>>3, o=u&7, h=o&3;
                P1[u] = ((f>>4)==h) ? ((o<4)?as1:ad1)[h*16+(f&15)] : 0.f; return; }
  u -= 512;
  if (u < 512){ int f=u>>3, o=u&7, h=o&3;
                const float* a=((o<4)?as2:ad2)+h*64; const float* w=W2+(size_t)f*256+h*64;
                float s=0.f; for(int c=0;c<64;c++) s=fmaf(w[c],a[c],s); P2[u]=s; return; }
  u -= 512;
  if (u < 2048){ int f=u>>3, o=u&7, h=o&3;
                 const float* a=((o<4)?as3:ad3)+h*128; const float* w=W3+(size_t)f*512+h*128;
                 float s=0.f; for(int c=0;c<128;c++) s=fmaf(w[c],a[c],s); P3[u]=s; }
}

__global__ void k_cvt_x(const float* __restrict__ x, f16* __restrict__ xh){
  int u = blockIdx.x*256 + threadIdx.x;
  if (u < NNODES*32){
    float4 v = *(const float4*)&x[(size_t)u*4];
    f16x4 o; o[0]=(f16)v.x; o[1]=(f16)v.y; o[2]=(f16)v.z; o[3]=(f16)v.w;
    *(f16x4*)&xh[(size_t)u*4] = o;
  }
}

// ---------------- scores: es/ed = g(f16) @ P(f32 [KF][8]) ----------------
template<int KF>
__global__ __launch_bounds__(256) void k_scores_h(const f16* __restrict__ g, const float* __restrict__ P,
                                                  float* __restrict__ es, float* __restrict__ ed){
  int n = blockIdx.x*4 + (threadIdx.x>>6);
  int lane = threadIdx.x & 63;
  if (n >= NNODES) return;
  constexpr int NI = KF/64;
  float v[NI];
  #pragma unroll
  for (int i=0;i<NI;i++) v[i] = (float)g[(size_t)n*KF + i*64 + lane];
  #pragma unroll
  for (int o=0;o<8;o++){
    float p=0.f;
    #pragma unroll
    for (int i=0;i<NI;i++) p = fmaf(v[i], P[(i*64+lane)*8+o], p);
    #pragma unroll
    for (int m=32;m>0;m>>=1) p += __shfl_xor(p, m, 64);
    if (lane==0){ if (o<4) es[n*4+o]=p; else ed[n*4+(o-4)]=p; }
  }
}

// ---------------- MFMA GEMMs ----------------
// l1: h1[50000,64] = xh[50000,128] @ BT1^T ; raw (no bias/act)
__global__ __launch_bounds__(256) void k_mfma_l1(const f16* __restrict__ xh, const f16* __restrict__ BT1,
                                                 f16* __restrict__ h1h){
  int wv = threadIdx.x>>6, lane = threadIdx.x&63;
  int r = lane&15, kb = lane>>4;
  int row0 = blockIdx.x*64 + wv*16;
  const f16* arow = xh + (size_t)(row0 + r)*128 + kb*8;
  f32x4 acc[4] = {{0,0,0,0},{0,0,0,0},{0,0,0,0},{0,0,0,0}};
  for (int k0=0;k0<128;k0+=32){
    f16x8 af = *(const f16x8*)(arow + k0);
    #pragma unroll
    for (int c=0;c<4;c++){
      f16x8 bf = *(const f16x8*)(BT1 + (size_t)(c*16+r)*128 + k0 + kb*8);
      acc[c] = __builtin_amdgcn_mfma_f32_16x16x32_f16(af, bf, acc[c], 0,0,0);
    }
  }
  #pragma unroll
  for (int c=0;c<4;c++)
    #pragma unroll
    for (int i=0;i<4;i++){
      int row = row0 + kb*4 + i;
      if (row < NNODES) h1h[(size_t)row*64 + c*16 + r] = (f16)acc[c][i];
    }
}

// l2 (per-head): g2[n, h*64+j] = ELU(agg2[n, h*64+:] @ W2_h + b2)
__global__ __launch_bounds__(256) void k_mfma_l2(const f16* __restrict__ agg2h, const f16* __restrict__ BT2,
                                                 const float* __restrict__ b2, f16* __restrict__ g2h){
  int wv = threadIdx.x>>6, lane = threadIdx.x&63;
  int r = lane&15, kb = lane>>4;
  int h = blockIdx.y;
  int row0 = blockIdx.x*64 + wv*16;
  const f16* arow = agg2h + (size_t)(row0 + r)*256 + h*64 + kb*8;
  f32x4 acc[4] = {{0,0,0,0},{0,0,0,0},{0,0,0,0},{0,0,0,0}};
  #pragma unroll
  for (int k0=0;k0<64;k0+=32){
    f16x8 af = *(const f16x8*)(arow + k0);
    #pragma unroll
    for (int c=0;c<4;c++){
      f16x8 bf = *(const f16x8*)(BT2 + (size_t)(h*64+c*16+r)*64 + k0 + kb*8);
      acc[c] = __builtin_amdgcn_mfma_f32_16x16x32_f16(af, bf, acc[c], 0,0,0);
    }
  }
  #pragma unroll
  for (int c=0;c<4;c++){
    int col = h*64 + c*16 + r;
    float bb = b2[col];
    #pragma unroll
    for (int i=0;i<4;i++){
      int row = row0 + kb*4 + i;
      if (row < NNODES) g2h[(size_t)row*256 + col] = (f16)eluf(acc[c][i] + bb);
    }
  }
}

// l3: g3[n,128] = ELU(0.25 * agg3[n,1024] @ BT3^T + b3)
__global__ __launch_bounds__(256) void k_mfma_l3(const f16* __restrict__ agg3h, const f16* __restrict__ BT3,
                                                 const float* __restrict__ b3, float* __restrict__ g3){
  int wv = threadIdx.x>>6, lane = threadIdx.x&63;
  int r = lane&15, kb = lane>>4;
  int row0 = blockIdx.x*128 + wv*32;
  const f16* a0 = agg3h + (size_t)(row0 + r)*1024 + kb*8;
  const f16* a1 = a0 + (size_t)16*1024;
  f32x4 acc[2][8];
  #pragma unroll
  for (int rt=0;rt<2;rt++)
    #pragma unroll
    for (int c=0;c<8;c++) acc[rt][c] = (f32x4){0,0,0,0};
  for (int k0=0;k0<1024;k0+=32){
    f16x8 af0 = *(const f16x8*)(a0 + k0);
    f16x8 af1 = *(const f16x8*)(a1 + k0);
    #pragma unroll
    for (int c=0;c<8;c++){
      f16x8 bf = *(const f16x8*)(BT3 + (size_t)(c*16+r)*1024 + k0 + kb*8);
      acc[0][c] = __builtin_amdgcn_mfma_f32_16x16x32_f16(af0, bf, acc[0][c], 0,0,0);
      acc[1][c] = __builtin_amdgcn_mfma_f32_16x16x32_f16(af1, bf, acc[1][c], 0,0,0);
    }
  }
  #pragma unroll
  for (int rt=0;rt<2;rt++)
    #pragma unroll
    for (int c=0;c<8;c++){
      int col = c*16 + r;
      float bb = b3[col];
      #pragma unroll
      for (int i=0;i<4;i++){
        int row = row0 + rt*16 + kb*4 + i;
        if (row < NNODES) g3[(size_t)row*128 + col] = eluf(0.25f*acc[rt][c][i] + bb);
      }
    }
}

// ---------------- gathers with fused exp/den (no segment-max; softmax shift-invariant) ----------------
__global__ __launch_bounds__(256) void k_gat1f(const f16* __restrict__ h1h, const float* __restrict__ es,
    const float* __restrict__ ed, const int* __restrict__ row_off, const int* __restrict__ csr_src,
    const float* __restrict__ b1, f16* __restrict__ g1h){
  int n = blockIdx.x*4 + (threadIdx.x>>6);
  if (n >= NNODES) return;
  int t = threadIdx.x & 63;
  int head = t >> 4;
  float edn = ed[n*4+head];
  int pos = row_off[n], end = row_off[n+1];
  float acc = 0.f, den = 0.f;
  for (; pos+1 < end; pos += 2){
    int s0 = csr_src[pos], s1 = csr_src[pos+1];
    float w0 = expf(lrelu(es[s0*4+head] + edn));
    float w1 = expf(lrelu(es[s1*4+head] + edn));
    float v0 = (float)h1h[(size_t)s0*64 + t];
    float v1 = (float)h1h[(size_t)s1*64 + t];
    acc = fmaf(w0, v0, fmaf(w1, v1, acc));
    den += w0 + w1;
  }
  if (pos < end){
    int s0 = csr_src[pos];
    float w0 = expf(lrelu(es[s0*4+head] + edn));
    acc = fmaf(w0, (float)h1h[(size_t)s0*64 + t], acc);
    den += w0;
  }
  g1h[(size_t)n*64 + t] = (f16)eluf(acc/(den + 1e-16f) + b1[t]);
}

__global__ __launch_bounds__(256) void k_agg2f(const f16* __restrict__ g1h, const float* __restrict__ es,
    const float* __restrict__ ed, const int* __restrict__ row_off, const int* __restrict__ csr_src,
    f16* __restrict__ agg2h){
  int n = blockIdx.x*4 + (threadIdx.x>>6);
  if (n >= NNODES) return;
  int t = threadIdx.x & 63;
  float4 edn = *(const float4*)&ed[n*4];
  int pos = row_off[n], end = row_off[n+1];
  float c0=0.f,c1=0.f,c2=0.f,c3=0.f,d0=0.f,d1=0.f,d2=0.f,d3=0.f;
  for (; pos+1 < end; pos += 2){
    int s0 = csr_src[pos], s1 = csr_src[pos+1];
    float4 a = *(const float4*)&es[s0*4];
    float4 b = *(const float4*)&es[s1*4];
    float v0 = (float)g1h[(size_t)s0*64 + t];
    float v1 = (float)g1h[(size_t)s1*64 + t];
    float w00=expf(lrelu(a.x+edn.x)), w01=expf(lrelu(a.y+edn.y)), w02=expf(lrelu(a.z+edn.z)), w03=expf(lrelu(a.w+edn.w));
    float w10=expf(lrelu(b.x+edn.x)), w11=expf(lrelu(b.y+edn.y)), w12=expf(lrelu(b.z+edn.z)), w13=expf(lrelu(b.w+edn.w));
    c0=fmaf(w00,v0,fmaf(w10,v1,c0)); c1=fmaf(w01,v0,fmaf(w11,v1,c1));
    c2=fmaf(w02,v0,fmaf(w12,v1,c2)); c3=fmaf(w03,v0,fmaf(w13,v1,c3));
    d0+=w00+w10; d1+=w01+w11; d2+=w02+w12; d3+=w03+w13;
  }
  if (pos < end){
    int s0 = csr_src[pos];
    float4 a = *(const float4*)&es[s0*4];
    float v0 = (float)g1h[(size_t)s0*64 + t];
    float w00=expf(lrelu(a.x+edn.x)), w01=expf(lrelu(a.y+edn.y)), w02=expf(lrelu(a.z+edn.z)), w03=expf(lrelu(a.w+edn.w));
    c0=fmaf(w00,v0,c0); c1=fmaf(w01,v0,c1); c2=fmaf(w02,v0,c2); c3=fmaf(w03,v0,c3);
    d0+=w00; d1+=w01; d2+=w02; d3+=w03;
  }
  size_t base = (size_t)n*256;
  agg2h[base       + t] = (f16)(c0/(d0+1e-16f));
  agg2h[base +  64 + t] = (f16)(c1/(d1+1e-16f));
  agg2h[base + 128 + t] = (f16)(c2/(d2+1e-16f));
  agg2h[base + 192 + t] = (f16)(c3/(d3+1e-16f));
}

__global__ __launch_bounds__(256) void k_agg3f(const f16* __restrict__ g2h, const float* __restrict__ es,
    const float* __restrict__ ed, const int* __restrict__ row_off, const int* __restrict__ csr_src,
    f16* __restrict__ agg3h){
  int n = blockIdx.x*4 + (threadIdx.x>>6);
  if (n >= NNODES) return;
  int lane = threadIdx.x & 63;
  float4 edn = *(const float4*)&ed[n*4];
  int pos = row_off[n], end = row_off[n+1];
  float acc[4][4] = {};
  float d0=0.f,d1=0.f,d2=0.f,d3=0.f;
  for (; pos+1 < end; pos += 2){
    int s0 = csr_src[pos], s1 = csr_src[pos+1];
    float4 a = *(const float4*)&es[s0*4];
    float4 b = *(const float4*)&es[s1*4];
    f16x4 u0 = *(const f16x4*)&g2h[(size_t)s0*256 + lane*4];
    f16x4 u1 = *(const f16x4*)&g2h[(size_t)s1*256 + lane*4];
    float w0[4] = {expf(lrelu(a.x+edn.x)), expf(lrelu(a.y+edn.y)), expf(lrelu(a.z+edn.z)), expf(lrelu(a.w+edn.w))};
    float w1[4] = {expf(lrelu(b.x+edn.x)), expf(lrelu(b.y+edn.y)), expf(lrelu(b.z+edn.z)), expf(lrelu(b.w+edn.w))};
    #pragma unroll
    for (int h=0;h<4;h++)
      #pragma unroll
      for (int j=0;j<4;j++)
        acc[h][j] = fmaf(w0[h], (float)u0[j], fmaf(w1[h], (float)u1[j], acc[h][j]));
    d0 += w0[0]+w1[0]; d1 += w0[1]+w1[1]; d2 += w0[2]+w1[2]; d3 += w0[3]+w1[3];
  }
  if (pos < end){
    int s0 = csr_src[pos];
    float4 a = *(const float4*)&es[s0*4];
    f16x4 u0 = *(const f16x4*)&g2h[(size_t)s0*256 + lane*4];
    float w0[4] = {expf(lrelu(a.x+edn.x)), expf(lrelu(a.y+edn.y)), expf(lrelu(a.z+edn.z)), expf(lrelu(a.w+edn.w))};
    #pragma unroll
    for (int h=0;h<4;h++)
      #pragma unroll
      for (int j=0;j<4;j++)
        acc[h][j] = fmaf(w0[h], (float)u0[j], acc[h][j]);
    d0 += w0[0]; d1 += w0[1]; d2 += w0[2]; d3 += w0[3];
  }
  float dn[4] = {d0+1e-16f, d1+1e-16f, d2+1e-16f, d3+1e-16f};
  #pragma unroll
  for (int h=0;h<4;h++){
    f16x4 o;
    #pragma unroll
    for (int j=0;j<4;j++) o[j] = (f16)(acc[h][j]/dn[h]);
    *(f16x4*)&agg3h[(size_t)n*1024 + h*256 + lane*4] = o;
  }
}

// ---------------- pooling + linear head ----------------
__device__ __forceinline__ int lowerb(const int* a, int n, int v){
  int lo=0, hi=n;
  while (lo<hi){ int mid=(lo+hi)>>1; if (a[mid]<v) lo=mid+1; else hi=mid; }
  return lo;
}
__global__ void k_pool8(const float* __restrict__ g3, const int* __restrict__ batch, float* __restrict__ pooledS){
  int g = blockIdx.x, ch = blockIdx.y, c = threadIdx.x; // 64 x 8 blocks, 128 threads
  int lo = lowerb(batch, NNODES, g);
  int hi = lowerb(batch, NNODES, g+1);
  int len = hi - lo;
  int b0 = lo + (len*ch)/8, b1 = lo + (len*(ch+1))/8;
  float s = 0.f;
  for (int nn=b0; nn<b1; ++nn) s += g3[(size_t)nn*128 + c];
  if (b1 > b0) atomicAdd(&pooledS[g*128+c], s);
}
__global__ void k_lin(const float* __restrict__ pooledS, const int* __restrict__ batch,
                      const float* __restrict__ Wlin, const float* __restrict__ blin, float* __restrict__ out){
  int t = threadIdx.x;
  if (t < 640){
    int g = t/10, j = t%10;
    int lo = lowerb(batch, NNODES, g);
    int hi = lowerb(batch, NNODES, g+1);
    float inv = 1.f / fmaxf((float)(hi-lo), 1.f);
    float s = blin[j];
    for (int c=0;c<128;c++) s = fmaf(pooledS[g*128+c]*inv, Wlin[c*10+j], s);
    out[t] = s;
  }
}

extern "C" void kernel_launch(void* const* d_in, const int* in_sizes, int n_in,
                              void* d_out, int out_size, void* d_ws, size_t ws_size,
                              hipStream_t stream){
  (void)in_sizes; (void)n_in; (void)out_size; (void)ws_size;
  const float* x    = (const float*)d_in[0];
  const int*   ei   = (const int*)d_in[1];
  const int*   batch= (const int*)d_in[2];
  const float* W1   = (const float*)d_in[3];
  const float* as1  = (const float*)d_in[4];
  const float* ad1  = (const float*)d_in[5];
  const float* b1   = (const float*)d_in[6];
  const float* W2   = (const float*)d_in[7];
  const float* as2  = (const float*)d_in[8];
  const float* ad2  = (const float*)d_in[9];
  const float* b2   = (const float*)d_in[10];
  const float* W3   = (const float*)d_in[11];
  const float* as3  = (const float*)d_in[12];
  const float* ad3  = (const float*)d_in[13];
  const float* b3   = (const float*)d_in[14];
  const float* Wlin = (const float*)d_in[15];
  const float* blin = (const float*)d_in[16];
  float* out = (float*)d_out;

  char* ws = (char*)d_ws;
  size_t off = 0;
  auto alloc = [&](size_t bytes)->char*{ char* p = ws + off; off += (bytes + 255) & ~(size_t)255; return p; };
  int* csr_src = (int*)alloc((size_t)ETOT*4);
  int* row_off = (int*)alloc((size_t)(NNODES+1)*4);
  int* deg     = (int*)alloc((size_t)NNODES*4);
  int* cursor  = (int*)alloc((size_t)NNODES*4);
  int* part    = (int*)alloc(256*4);
  int* bpre    = (int*)alloc(256*4);
  float* es    = (float*)alloc((size_t)NNODES*4*4);
  float* ed    = (float*)alloc((size_t)NNODES*4*4);
  f16* BT1     = (f16*)alloc(8192*2);
  f16* BT2     = (f16*)alloc(16384*2);
  f16* BT3     = (f16*)alloc(131072*2);
  float* P1    = (float*)alloc(512*4);
  float* P2    = (float*)alloc(512*4);
  float* P3    = (float*)alloc(2048*4);
  float* pooledS = (float*)alloc((size_t)NGRAPHS*128*4);
  f16* xh      = (f16*)alloc((size_t)NNODES*128*2);   // 12.8 MB
  f16* h1h     = (f16*)alloc((size_t)NNODES*64*2);    //  6.4 MB (absorbs xh OOB-read tail)
  f16* g1h     = (f16*)alloc((size_t)NNODES*64*2);    //  6.4 MB
  f16* agg2h   = (f16*)alloc((size_t)NNODES*256*2);   // 25.6 MB
  f16* g2h     = (f16*)alloc((size_t)NNODES*256*2);   // 25.6 MB (absorbs agg2h OOB-read tail)
  f16* agg3h   = (f16*)alloc((size_t)NNODES*1024*2);  // 102.4 MB
  float* g3    = (float*)alloc((size_t)NNODES*128*4); // 25.6 MB (absorbs agg3h OOB-read tail)

  int nbE = (NEDGES+255)/256;
  int nbS = (NNODES+255)/256;
  int nb4 = (NNODES+3)/4;

  // CSR with self-loop at slot 0 of each row
  k_one<<<nbS,256,0,stream>>>(deg);
  k_hist<<<nbE,256,0,stream>>>(ei, deg);
  k_scan1<<<nbS,256,0,stream>>>(deg, part, NNODES);
  k_scan2<<<1,256,0,stream>>>(part, bpre, row_off+NNODES, nbS);
  k_scan3<<<nbS,256,0,stream>>>(deg, bpre, row_off, NNODES);
  k_selfpos<<<nbS,256,0,stream>>>(row_off, csr_src, cursor);
  k_scatter<<<nbE,256,0,stream>>>(ei, row_off, cursor, csr_src);

  // weight prep + x cast
  k_prep<<<620,256,0,stream>>>(W1,W2,W3,as1,ad1,as2,ad2,as3,ad3,BT1,BT2,BT3,P1,P2,P3);
  k_cvt_x<<<6250,256,0,stream>>>(x, xh);

  // layer 1
  k_mfma_l1<<<782,256,0,stream>>>(xh, BT1, h1h);
  k_scores_h<64><<<nb4,256,0,stream>>>(h1h, P1, es, ed);
  k_gat1f<<<nb4,256,0,stream>>>(h1h, es, ed, row_off, csr_src, b1, g1h);

  // layer 2
  k_scores_h<64><<<nb4,256,0,stream>>>(g1h, P2, es, ed);
  k_agg2f<<<nb4,256,0,stream>>>(g1h, es, ed, row_off, csr_src, agg2h);
  k_mfma_l2<<<dim3(782,4),256,0,stream>>>(agg2h, BT2, b2, g2h);

  // layer 3
  k_scores_h<256><<<nb4,256,0,stream>>>(g2h, P3, es, ed);
  k_agg3f<<<nb4,256,0,stream>>>(g2h, es, ed, row_off, csr_src, agg3h);
  k_mfma_l3<<<391,256,0,stream>>>(agg3h, BT3, b3, g3);

  // pool + linear
  hipMemsetAsync(pooledS, 0, (size_t)NGRAPHS*128*4, stream);
  k_pool8<<<dim3(NGRAPHS,8),128,0,stream>>>(g3, batch, pooledS);
  k_lin<<<1,1024,0,stream>>>(pooledS, batch, Wlin, blin, out);
}

// Round 4
// 456.998 us; speedup vs baseline: 3.3281x; 1.5482x over previous
//
#include <hip/hip_runtime.h>
#include <math.h>

#define NNODES 50000
#define NEDGES 400000
#define ETOT   (NEDGES + NNODES)
#define NGRAPHS 64

typedef _Float16 f16;
typedef _Float16 f16x4 __attribute__((ext_vector_type(4)));
typedef _Float16 f16x8 __attribute__((ext_vector_type(8)));
typedef float f32x4 __attribute__((ext_vector_type(4)));

__device__ __forceinline__ float lrelu(float x){ return x >= 0.f ? x : 0.2f*x; }
__device__ __forceinline__ float eluf(float x){ return x > 0.f ? x : expm1f(x); }

// ---------------- CSR build (self-loop at slot 0 of each row) ----------------
__global__ void k_one(int* __restrict__ deg){
  int i = blockIdx.x*256 + threadIdx.x;
  if (i < NNODES) deg[i] = 1;
}
__global__ void k_hist(const int* __restrict__ ei, int* __restrict__ deg){
  int e = blockIdx.x*blockDim.x + threadIdx.x;
  if (e < NEDGES) atomicAdd(&deg[ei[NEDGES + e]], 1);
}
__global__ void k_scan1(const int* __restrict__ deg, int* __restrict__ part, int n){
  __shared__ int buf[256];
  int i = blockIdx.x*256 + threadIdx.x;
  buf[threadIdx.x] = (i<n)? deg[i] : 0;
  __syncthreads();
  for (int s=128; s>0; s>>=1){ if (threadIdx.x < s) buf[threadIdx.x]+=buf[threadIdx.x+s]; __syncthreads(); }
  if (threadIdx.x==0) part[blockIdx.x]=buf[0];
}
__global__ void k_scan2(const int* __restrict__ part, int* __restrict__ bpre, int* __restrict__ row_off_last, int nb){
  __shared__ int buf[256];
  int t = threadIdx.x;
  int v = (t<nb)? part[t] : 0;
  buf[t]=v; __syncthreads();
  for (int s=1;s<256;s<<=1){ int a = (t>=s)? buf[t-s]:0; __syncthreads(); buf[t]+=a; __syncthreads(); }
  if (t<nb) bpre[t] = buf[t]-v;
  if (t==255) row_off_last[0] = buf[255];
}
__global__ void k_scan3(const int* __restrict__ deg, const int* __restrict__ bpre, int* __restrict__ row_off, int n){
  __shared__ int buf[256];
  int t = threadIdx.x;
  int i = blockIdx.x*256 + t;
  int v = (i<n)? deg[i]:0;
  buf[t]=v; __syncthreads();
  for (int s=1;s<256;s<<=1){ int a=(t>=s)?buf[t-s]:0; __syncthreads(); buf[t]+=a; __syncthreads(); }
  if (i<n) row_off[i] = bpre[blockIdx.x] + buf[t]-v;
}
__global__ void k_selfpos(const int* __restrict__ row_off, int* __restrict__ csr_src, int* __restrict__ cursor){
  int n = blockIdx.x*256 + threadIdx.x;
  if (n < NNODES){
    csr_src[row_off[n]] = n;
    cursor[n] = 1;
  }
}
__global__ void k_scatter(const int* __restrict__ ei, const int* __restrict__ row_off,
                          int* __restrict__ cursor, int* __restrict__ csr_src){
  int e = blockIdx.x*blockDim.x + threadIdx.x;
  if (e < NEDGES){
    int s = ei[e], d = ei[NEDGES+e];
    int pos = row_off[d] + atomicAdd(&cursor[d],1);
    csr_src[pos] = s;
  }
}

// ---------------- weight prep: BT* (f16 col-major), PT* (f16 [16][KF], rows 8..15 zero) ----------------
__global__ void k_prep(const float* __restrict__ W1, const float* __restrict__ W2, const float* __restrict__ W3,
                       const float* __restrict__ as1, const float* __restrict__ ad1,
                       const float* __restrict__ as2, const float* __restrict__ ad2,
                       const float* __restrict__ as3, const float* __restrict__ ad3,
                       f16* __restrict__ BT1, f16* __restrict__ BT2, f16* __restrict__ BT3,
                       f16* __restrict__ PT1, f16* __restrict__ PT2, f16* __restrict__ PT3){
  int u = blockIdx.x*256 + threadIdx.x;
  if (u < 8192){ int j=u>>7, k=u&127; BT1[j*128+k] = (f16)W1[(size_t)k*64+j]; return; }
  u -= 8192;
  if (u < 16384){ int col=u>>6, k=u&63; BT2[col*64+k] = (f16)W2[(size_t)k*256+col]; return; }
  u -= 16384;
  if (u < 131072){ int j=u>>10, t=u&1023, h=t>>8, k=t&255;
                   BT3[(size_t)j*1024+t] = (f16)W3[(size_t)k*512 + h*128 + j]; return; }
  u -= 131072;
  if (u < 1024){ // PT1[o][k], layer1 is block-diagonal: head h owns feats h*16..h*16+15
    int o=u>>6, k=u&63; float v=0.f;
    if (o<8){ int h=o&3; if ((k>>4)==h) v = ((o<4)?as1:ad1)[h*16 + (k&15)]; }
    PT1[u] = (f16)v; return; }
  u -= 1024;
  if (u < 1024){ // PT2[o][k] = sum_c W2[k, h*64+c] * a2_h[c]
    int o=u>>6, k=u&63; float v=0.f;
    if (o<8){ int h=o&3;
      const float* a=((o<4)?as2:ad2)+h*64; const float* w=W2+(size_t)k*256+h*64;
      for(int c=0;c<64;c++) v=fmaf(w[c],a[c],v); }
    PT2[u] = (f16)v; return; }
  u -= 1024;
  if (u < 4096){ // PT3[o][k] = sum_c W3[k, h*128+c] * a3_h[c]
    int o=u>>8, k=u&255; float v=0.f;
    if (o<8){ int h=o&3;
      const float* a=((o<4)?as3:ad3)+h*128; const float* w=W3+(size_t)k*512+h*128;
      for(int c=0;c<128;c++) v=fmaf(w[c],a[c],v); }
    PT3[u] = (f16)v; }
}

__global__ void k_cvt_x(const float* __restrict__ x, f16* __restrict__ xh){
  int u = blockIdx.x*256 + threadIdx.x;
  if (u < NNODES*32){
    float4 v = *(const float4*)&x[(size_t)u*4];
    f16x4 o; o[0]=(f16)v.x; o[1]=(f16)v.y; o[2]=(f16)v.z; o[3]=(f16)v.w;
    *(f16x4*)&xh[(size_t)u*4] = o;
  }
}

// ---------------- scores via MFMA: esd[n][0..3]=es, [4..7]=ed ----------------
template<int KF>
__global__ __launch_bounds__(256) void k_scores_m(const f16* __restrict__ g, const f16* __restrict__ PT,
                                                  float* __restrict__ esd){
  int wv = threadIdx.x>>6, lane = threadIdx.x&63;
  int r = lane&15, kb = lane>>4;
  int row0 = blockIdx.x*64 + wv*16;
  const f16* arow = g + (size_t)(row0+r)*KF + kb*8;
  const f16* brow = PT + (size_t)r*KF + kb*8;
  f32x4 acc = {0,0,0,0};
  #pragma unroll
  for (int k0=0;k0<KF;k0+=32){
    f16x8 af = *(const f16x8*)(arow + k0);
    f16x8 bf = *(const f16x8*)(brow + k0);
    acc = __builtin_amdgcn_mfma_f32_16x16x32_f16(af, bf, acc, 0,0,0);
  }
  if (r < 8){
    #pragma unroll
    for (int i=0;i<4;i++){
      int row = row0 + kb*4 + i;
      if (row < NNODES) esd[(size_t)row*8 + r] = acc[i];
    }
  }
}

// ---------------- MFMA GEMMs ----------------
// l1: h1[50000,64] = xh[50000,128] @ BT1^T ; raw (no bias/act)
__global__ __launch_bounds__(256) void k_mfma_l1(const f16* __restrict__ xh, const f16* __restrict__ BT1,
                                                 f16* __restrict__ h1h){
  int wv = threadIdx.x>>6, lane = threadIdx.x&63;
  int r = lane&15, kb = lane>>4;
  int row0 = blockIdx.x*64 + wv*16;
  const f16* arow = xh + (size_t)(row0 + r)*128 + kb*8;
  f32x4 acc[4] = {{0,0,0,0},{0,0,0,0},{0,0,0,0},{0,0,0,0}};
  for (int k0=0;k0<128;k0+=32){
    f16x8 af = *(const f16x8*)(arow + k0);
    #pragma unroll
    for (int c=0;c<4;c++){
      f16x8 bf = *(const f16x8*)(BT1 + (size_t)(c*16+r)*128 + k0 + kb*8);
      acc[c] = __builtin_amdgcn_mfma_f32_16x16x32_f16(af, bf, acc[c], 0,0,0);
    }
  }
  #pragma unroll
  for (int c=0;c<4;c++)
    #pragma unroll
    for (int i=0;i<4;i++){
      int row = row0 + kb*4 + i;
      if (row < NNODES) h1h[(size_t)row*64 + c*16 + r] = (f16)acc[c][i];
    }
}

// l2 (per-head): g2[n, h*64+j] = ELU(agg2[n, h*64+:] @ W2_h + b2)
__global__ __launch_bounds__(256) void k_mfma_l2(const f16* __restrict__ agg2h, const f16* __restrict__ BT2,
                                                 const float* __restrict__ b2, f16* __restrict__ g2h){
  int wv = threadIdx.x>>6, lane = threadIdx.x&63;
  int r = lane&15, kb = lane>>4;
  int h = blockIdx.y;
  int row0 = blockIdx.x*64 + wv*16;
  const f16* arow = agg2h + (size_t)(row0 + r)*256 + h*64 + kb*8;
  f32x4 acc[4] = {{0,0,0,0},{0,0,0,0},{0,0,0,0},{0,0,0,0}};
  #pragma unroll
  for (int k0=0;k0<64;k0+=32){
    f16x8 af = *(const f16x8*)(arow + k0);
    #pragma unroll
    for (int c=0;c<4;c++){
      f16x8 bf = *(const f16x8*)(BT2 + (size_t)(h*64+c*16+r)*64 + k0 + kb*8);
      acc[c] = __builtin_amdgcn_mfma_f32_16x16x32_f16(af, bf, acc[c], 0,0,0);
    }
  }
  #pragma unroll
  for (int c=0;c<4;c++){
    int col = h*64 + c*16 + r;
    float bb = b2[col];
    #pragma unroll
    for (int i=0;i<4;i++){
      int row = row0 + kb*4 + i;
      if (row < NNODES) g2h[(size_t)row*256 + col] = (f16)eluf(acc[c][i] + bb);
    }
  }
}

// l3: g3[n,128] = ELU(0.25 * agg3[n,1024] @ BT3^T + b3)
__global__ __launch_bounds__(256) void k_mfma_l3(const f16* __restrict__ agg3h, const f16* __restrict__ BT3,
                                                 const float* __restrict__ b3, float* __restrict__ g3){
  int wv = threadIdx.x>>6, lane = threadIdx.x&63;
  int r = lane&15, kb = lane>>4;
  int row0 = blockIdx.x*128 + wv*32;
  const f16* a0 = agg3h + (size_t)(row0 + r)*1024 + kb*8;
  const f16* a1 = a0 + (size_t)16*1024;
  f32x4 acc[2][8];
  #pragma unroll
  for (int rt=0;rt<2;rt++)
    #pragma unroll
    for (int c=0;c<8;c++) acc[rt][c] = (f32x4){0,0,0,0};
  for (int k0=0;k0<1024;k0+=32){
    f16x8 af0 = *(const f16x8*)(a0 + k0);
    f16x8 af1 = *(const f16x8*)(a1 + k0);
    #pragma unroll
    for (int c=0;c<8;c++){
      f16x8 bf = *(const f16x8*)(BT3 + (size_t)(c*16+r)*1024 + k0 + kb*8);
      acc[0][c] = __builtin_amdgcn_mfma_f32_16x16x32_f16(af0, bf, acc[0][c], 0,0,0);
      acc[1][c] = __builtin_amdgcn_mfma_f32_16x16x32_f16(af1, bf, acc[1][c], 0,0,0);
    }
  }
  #pragma unroll
  for (int rt=0;rt<2;rt++)
    #pragma unroll
    for (int c=0;c<8;c++){
      int col = c*16 + r;
      float bb = b3[col];
      #pragma unroll
      for (int i=0;i<4;i++){
        int row = row0 + rt*16 + kb*4 + i;
        if (row < NNODES) g3[(size_t)row*128 + col] = eluf(0.25f*acc[rt][c][i] + bb);
      }
    }
}

// ---------------- gathers with fused exp/den (no segment-max; softmax shift-invariant) ----------------
__global__ __launch_bounds__(256) void k_gat1f(const f16* __restrict__ h1h, const float* __restrict__ esd,
    const int* __restrict__ row_off, const int* __restrict__ csr_src,
    const float* __restrict__ b1, f16* __restrict__ g1h){
  int n = blockIdx.x*4 + (threadIdx.x>>6);
  if (n >= NNODES) return;
  int t = threadIdx.x & 63;
  int head = t >> 4;
  float edn = esd[n*8+4+head];
  int pos = row_off[n], end = row_off[n+1];
  float acc = 0.f, den = 0.f;
  for (; pos+1 < end; pos += 2){
    int s0 = csr_src[pos], s1 = csr_src[pos+1];
    float w0 = expf(lrelu(esd[s0*8+head] + edn));
    float w1 = expf(lrelu(esd[s1*8+head] + edn));
    float v0 = (float)h1h[(size_t)s0*64 + t];
    float v1 = (float)h1h[(size_t)s1*64 + t];
    acc = fmaf(w0, v0, fmaf(w1, v1, acc));
    den += w0 + w1;
  }
  if (pos < end){
    int s0 = csr_src[pos];
    float w0 = expf(lrelu(esd[s0*8+head] + edn));
    acc = fmaf(w0, (float)h1h[(size_t)s0*64 + t], acc);
    den += w0;
  }
  g1h[(size_t)n*64 + t] = (f16)eluf(acc/(den + 1e-16f) + b1[t]);
}

__global__ __launch_bounds__(256) void k_agg2f(const f16* __restrict__ g1h, const float* __restrict__ esd,
    const int* __restrict__ row_off, const int* __restrict__ csr_src,
    f16* __restrict__ agg2h){
  int n = blockIdx.x*4 + (threadIdx.x>>6);
  if (n >= NNODES) return;
  int t = threadIdx.x & 63;
  float4 edn = *(const float4*)&esd[n*8+4];
  int pos = row_off[n], end = row_off[n+1];
  float c0=0.f,c1=0.f,c2=0.f,c3=0.f,d0=0.f,d1=0.f,d2=0.f,d3=0.f;
  for (; pos+1 < end; pos += 2){
    int s0 = csr_src[pos], s1 = csr_src[pos+1];
    float4 a = *(const float4*)&esd[s0*8];
    float4 b = *(const float4*)&esd[s1*8];
    float v0 = (float)g1h[(size_t)s0*64 + t];
    float v1 = (float)g1h[(size_t)s1*64 + t];
    float w00=expf(lrelu(a.x+edn.x)), w01=expf(lrelu(a.y+edn.y)), w02=expf(lrelu(a.z+edn.z)), w03=expf(lrelu(a.w+edn.w));
    float w10=expf(lrelu(b.x+edn.x)), w11=expf(lrelu(b.y+edn.y)), w12=expf(lrelu(b.z+edn.z)), w13=expf(lrelu(b.w+edn.w));
    c0=fmaf(w00,v0,fmaf(w10,v1,c0)); c1=fmaf(w01,v0,fmaf(w11,v1,c1));
    c2=fmaf(w02,v0,fmaf(w12,v1,c2)); c3=fmaf(w03,v0,fmaf(w13,v1,c3));
    d0+=w00+w10; d1+=w01+w11; d2+=w02+w12; d3+=w03+w13;
  }
  if (pos < end){
    int s0 = csr_src[pos];
    float4 a = *(const float4*)&esd[s0*8];
    float v0 = (float)g1h[(size_t)s0*64 + t];
    float w00=expf(lrelu(a.x+edn.x)), w01=expf(lrelu(a.y+edn.y)), w02=expf(lrelu(a.z+edn.z)), w03=expf(lrelu(a.w+edn.w));
    c0=fmaf(w00,v0,c0); c1=fmaf(w01,v0,c1); c2=fmaf(w02,v0,c2); c3=fmaf(w03,v0,c3);
    d0+=w00; d1+=w01; d2+=w02; d3+=w03;
  }
  size_t base = (size_t)n*256;
  agg2h[base       + t] = (f16)(c0/(d0+1e-16f));
  agg2h[base +  64 + t] = (f16)(c1/(d1+1e-16f));
  agg2h[base + 128 + t] = (f16)(c2/(d2+1e-16f));
  agg2h[base + 192 + t] = (f16)(c3/(d3+1e-16f));
}

__global__ __launch_bounds__(256) void k_agg3f(const f16* __restrict__ g2h, const float* __restrict__ esd,
    const int* __restrict__ row_off, const int* __restrict__ csr_src,
    f16* __restrict__ agg3h){
  int n = blockIdx.x*4 + (threadIdx.x>>6);
  if (n >= NNODES) return;
  int lane = threadIdx.x & 63;
  float4 edn = *(const float4*)&esd[n*8+4];
  int pos = row_off[n], end = row_off[n+1];
  float acc[4][4] = {};
  float d0=0.f,d1=0.f,d2=0.f,d3=0.f;
  for (; pos+1 < end; pos += 2){
    int s0 = csr_src[pos], s1 = csr_src[pos+1];
    float4 a = *(const float4*)&esd[s0*8];
    float4 b = *(const float4*)&esd[s1*8];
    f16x4 u0 = *(const f16x4*)&g2h[(size_t)s0*256 + lane*4];
    f16x4 u1 = *(const f16x4*)&g2h[(size_t)s1*256 + lane*4];
    float w0[4] = {expf(lrelu(a.x+edn.x)), expf(lrelu(a.y+edn.y)), expf(lrelu(a.z+edn.z)), expf(lrelu(a.w+edn.w))};
    float w1[4] = {expf(lrelu(b.x+edn.x)), expf(lrelu(b.y+edn.y)), expf(lrelu(b.z+edn.z)), expf(lrelu(b.w+edn.w))};
    #pragma unroll
    for (int h=0;h<4;h++)
      #pragma unroll
      for (int j=0;j<4;j++)
        acc[h][j] = fmaf(w0[h], (float)u0[j], fmaf(w1[h], (float)u1[j], acc[h][j]));
    d0 += w0[0]+w1[0]; d1 += w0[1]+w1[1]; d2 += w0[2]+w1[2]; d3 += w0[3]+w1[3];
  }
  if (pos < end){
    int s0 = csr_src[pos];
    float4 a = *(const float4*)&esd[s0*8];
    f16x4 u0 = *(const f16x4*)&g2h[(size_t)s0*256 + lane*4];
    float w0[4] = {expf(lrelu(a.x+edn.x)), expf(lrelu(a.y+edn.y)), expf(lrelu(a.z+edn.z)), expf(lrelu(a.w+edn.w))};
    #pragma unroll
    for (int h=0;h<4;h++)
      #pragma unroll
      for (int j=0;j<4;j++)
        acc[h][j] = fmaf(w0[h], (float)u0[j], acc[h][j]);
    d0 += w0[0]; d1 += w0[1]; d2 += w0[2]; d3 += w0[3];
  }
  float dn[4] = {d0+1e-16f, d1+1e-16f, d2+1e-16f, d3+1e-16f};
  #pragma unroll
  for (int h=0;h<4;h++){
    f16x4 o;
    #pragma unroll
    for (int j=0;j<4;j++) o[j] = (f16)(acc[h][j]/dn[h]);
    *(f16x4*)&agg3h[(size_t)n*1024 + h*256 + lane*4] = o;
  }
}

// ---------------- pooling + linear head ----------------
__device__ __forceinline__ int lowerb(const int* a, int n, int v){
  int lo=0, hi=n;
  while (lo<hi){ int mid=(lo+hi)>>1; if (a[mid]<v) lo=mid+1; else hi=mid; }
  return lo;
}
__global__ void k_pool8(const float* __restrict__ g3, const int* __restrict__ batch, float* __restrict__ pooledS){
  int g = blockIdx.x, ch = blockIdx.y, c = threadIdx.x; // 64 x 8 blocks, 128 threads
  int lo = lowerb(batch, NNODES, g);
  int hi = lowerb(batch, NNODES, g+1);
  int len = hi - lo;
  int b0 = lo + (len*ch)/8, b1 = lo + (len*(ch+1))/8;
  float s = 0.f;
  for (int nn=b0; nn<b1; ++nn) s += g3[(size_t)nn*128 + c];
  if (b1 > b0) atomicAdd(&pooledS[g*128+c], s);
}
__global__ void k_lin(const float* __restrict__ pooledS, const int* __restrict__ batch,
                      const float* __restrict__ Wlin, const float* __restrict__ blin, float* __restrict__ out){
  int t = threadIdx.x;
  if (t < 640){
    int g = t/10, j = t%10;
    int lo = lowerb(batch, NNODES, g);
    int hi = lowerb(batch, NNODES, g+1);
    float inv = 1.f / fmaxf((float)(hi-lo), 1.f);
    float s = blin[j];
    for (int c=0;c<128;c++) s = fmaf(pooledS[g*128+c]*inv, Wlin[c*10+j], s);
    out[t] = s;
  }
}

extern "C" void kernel_launch(void* const* d_in, const int* in_sizes, int n_in,
                              void* d_out, int out_size, void* d_ws, size_t ws_size,
                              hipStream_t stream){
  (void)in_sizes; (void)n_in; (void)out_size; (void)ws_size;
  const float* x    = (const float*)d_in[0];
  const int*   ei   = (const int*)d_in[1];
  const int*   batch= (const int*)d_in[2];
  const float* W1   = (const float*)d_in[3];
  const float* as1  = (const float*)d_in[4];
  const float* ad1  = (const float*)d_in[5];
  const float* b1   = (const float*)d_in[6];
  const float* W2   = (const float*)d_in[7];
  const float* as2  = (const float*)d_in[8];
  const float* ad2  = (const float*)d_in[9];
  const float* b2   = (const float*)d_in[10];
  const float* W3   = (const float*)d_in[11];
  const float* as3  = (const float*)d_in[12];
  const float* ad3  = (const float*)d_in[13];
  const float* b3   = (const float*)d_in[14];
  const float* Wlin = (const float*)d_in[15];
  const float* blin = (const float*)d_in[16];
  float* out = (float*)d_out;

  char* ws = (char*)d_ws;
  size_t off = 0;
  auto alloc = [&](size_t bytes)->char*{ char* p = ws + off; off += (bytes + 255) & ~(size_t)255; return p; };
  int* csr_src = (int*)alloc((size_t)ETOT*4);
  int* row_off = (int*)alloc((size_t)(NNODES+1)*4);
  int* deg     = (int*)alloc((size_t)NNODES*4);
  int* cursor  = (int*)alloc((size_t)NNODES*4);
  int* part    = (int*)alloc(256*4);
  int* bpre    = (int*)alloc(256*4);
  float* esd   = (float*)alloc((size_t)NNODES*8*4);
  f16* BT1     = (f16*)alloc(8192*2);
  f16* BT2     = (f16*)alloc(16384*2);
  f16* BT3     = (f16*)alloc(131072*2);
  f16* PT1     = (f16*)alloc(1024*2);
  f16* PT2     = (f16*)alloc(1024*2);
  f16* PT3     = (f16*)alloc(4096*2);
  float* pooledS = (float*)alloc((size_t)NGRAPHS*128*4);
  f16* xh      = (f16*)alloc((size_t)NNODES*128*2);   // 12.8 MB
  f16* h1h     = (f16*)alloc((size_t)NNODES*64*2);    //  6.4 MB (absorbs OOB-read tails)
  f16* g1h     = (f16*)alloc((size_t)NNODES*64*2);    //  6.4 MB
  f16* agg2h   = (f16*)alloc((size_t)NNODES*256*2);   // 25.6 MB
  f16* g2h     = (f16*)alloc((size_t)NNODES*256*2);   // 25.6 MB
  f16* agg3h   = (f16*)alloc((size_t)NNODES*1024*2);  // 102.4 MB
  float* g3    = (float*)alloc((size_t)NNODES*128*4); // 25.6 MB

  int nbE = (NEDGES+255)/256;
  int nbS = (NNODES+255)/256;
  int nb4 = (NNODES+3)/4;

  // CSR with self-loop at slot 0 of each row
  k_one<<<nbS,256,0,stream>>>(deg);
  k_hist<<<nbE,256,0,stream>>>(ei, deg);
  k_scan1<<<nbS,256,0,stream>>>(deg, part, NNODES);
  k_scan2<<<1,256,0,stream>>>(part, bpre, row_off+NNODES, nbS);
  k_scan3<<<nbS,256,0,stream>>>(deg, bpre, row_off, NNODES);
  k_selfpos<<<nbS,256,0,stream>>>(row_off, csr_src, cursor);
  k_scatter<<<nbE,256,0,stream>>>(ei, row_off, cursor, csr_src);

  // weight prep + x cast
  k_prep<<<632,256,0,stream>>>(W1,W2,W3,as1,ad1,as2,ad2,as3,ad3,BT1,BT2,BT3,PT1,PT2,PT3);
  k_cvt_x<<<6250,256,0,stream>>>(x, xh);

  // layer 1
  k_mfma_l1<<<782,256,0,stream>>>(xh, BT1, h1h);
  k_scores_m<64><<<782,256,0,stream>>>(h1h, PT1, esd);
  k_gat1f<<<nb4,256,0,stream>>>(h1h, esd, row_off, csr_src, b1, g1h);

  // layer 2
  k_scores_m<64><<<782,256,0,stream>>>(g1h, PT2, esd);
  k_agg2f<<<nb4,256,0,stream>>>(g1h, esd, row_off, csr_src, agg2h);
  k_mfma_l2<<<dim3(782,4),256,0,stream>>>(agg2h, BT2, b2, g2h);

  // layer 3
  k_scores_m<256><<<782,256,0,stream>>>(g2h, PT3, esd);
  k_agg3f<<<nb4,256,0,stream>>>(g2h, esd, row_off, csr_src, agg3h);
  k_mfma_l3<<<391,256,0,stream>>>(agg3h, BT3, b3, g3);

  // pool + linear
  hipMemsetAsync(pooledS, 0, (size_t)NGRAPHS*128*4, stream);
  k_pool8<<<dim3(NGRAPHS,8),128,0,stream>>>(g3, batch, pooledS);
  k_lin<<<1,1024,0,stream>>>(pooledS, batch, Wlin, blin, out);
}

// Round 5
// 411.670 us; speedup vs baseline: 3.6946x; 1.1101x over previous
//
#include <hip/hip_runtime.h>
#include <math.h>

#define NNODES 50000
#define NEDGES 400000
#define ETOT   (NEDGES + NNODES)
#define NGRAPHS 64

typedef _Float16 f16;
typedef _Float16 f16x4 __attribute__((ext_vector_type(4)));
typedef _Float16 f16x8 __attribute__((ext_vector_type(8)));
typedef float f32x4 __attribute__((ext_vector_type(4)));

__device__ __forceinline__ float lrelu(float x){ return x >= 0.f ? x : 0.2f*x; }
__device__ __forceinline__ float eluf(float x){ return x > 0.f ? x : expm1f(x); }

// ---------------- CSR build (self-loop at slot 0 of each row) ----------------
__global__ void k_one(int* __restrict__ deg){
  int i = blockIdx.x*256 + threadIdx.x;
  if (i < NNODES) deg[i] = 1;
}
__global__ void k_hist(const int* __restrict__ ei, int* __restrict__ deg){
  int e = blockIdx.x*blockDim.x + threadIdx.x;
  if (e < NEDGES) atomicAdd(&deg[ei[NEDGES + e]], 1);
}
__global__ void k_scan1(const int* __restrict__ deg, int* __restrict__ part, int n){
  __shared__ int buf[256];
  int i = blockIdx.x*256 + threadIdx.x;
  buf[threadIdx.x] = (i<n)? deg[i] : 0;
  __syncthreads();
  for (int s=128; s>0; s>>=1){ if (threadIdx.x < s) buf[threadIdx.x]+=buf[threadIdx.x+s]; __syncthreads(); }
  if (threadIdx.x==0) part[blockIdx.x]=buf[0];
}
__global__ void k_scan2(const int* __restrict__ part, int* __restrict__ bpre, int* __restrict__ row_off_last, int nb){
  __shared__ int buf[256];
  int t = threadIdx.x;
  int v = (t<nb)? part[t] : 0;
  buf[t]=v; __syncthreads();
  for (int s=1;s<256;s<<=1){ int a = (t>=s)? buf[t-s]:0; __syncthreads(); buf[t]+=a; __syncthreads(); }
  if (t<nb) bpre[t] = buf[t]-v;
  if (t==255) row_off_last[0] = buf[255];
}
__global__ void k_scan3(const int* __restrict__ deg, const int* __restrict__ bpre, int* __restrict__ row_off, int n){
  __shared__ int buf[256];
  int t = threadIdx.x;
  int i = blockIdx.x*256 + t;
  int v = (i<n)? deg[i]:0;
  buf[t]=v; __syncthreads();
  for (int s=1;s<256;s<<=1){ int a=(t>=s)?buf[t-s]:0; __syncthreads(); buf[t]+=a; __syncthreads(); }
  if (i<n) row_off[i] = bpre[blockIdx.x] + buf[t]-v;
}
__global__ void k_selfpos(const int* __restrict__ row_off, int* __restrict__ csr_src,
                          int* __restrict__ csr_dst, int* __restrict__ cursor){
  int n = blockIdx.x*256 + threadIdx.x;
  if (n < NNODES){
    int p = row_off[n];
    csr_src[p] = n; csr_dst[p] = n;
    cursor[n] = 1;
  }
}
__global__ void k_scatter(const int* __restrict__ ei, const int* __restrict__ row_off,
                          int* __restrict__ cursor, int* __restrict__ csr_src, int* __restrict__ csr_dst){
  int e = blockIdx.x*blockDim.x + threadIdx.x;
  if (e < NEDGES){
    int s = ei[e], d = ei[NEDGES+e];
    int pos = row_off[d] + atomicAdd(&cursor[d],1);
    csr_src[pos] = s; csr_dst[pos] = d;
  }
}

// ---------------- weight prep: BT* (f16 col-major), PT* (f16 [16][KF], rows 8..15 zero) ----------------
__global__ void k_prep(const float* __restrict__ W1, const float* __restrict__ W2, const float* __restrict__ W3,
                       const float* __restrict__ as1, const float* __restrict__ ad1,
                       const float* __restrict__ as2, const float* __restrict__ ad2,
                       const float* __restrict__ as3, const float* __restrict__ ad3,
                       f16* __restrict__ BT1, f16* __restrict__ BT2, f16* __restrict__ BT3,
                       f16* __restrict__ PT1, f16* __restrict__ PT2, f16* __restrict__ PT3){
  int u = blockIdx.x*256 + threadIdx.x;
  if (u < 8192){ int j=u>>7, k=u&127; BT1[j*128+k] = (f16)W1[(size_t)k*64+j]; return; }
  u -= 8192;
  if (u < 16384){ int col=u>>6, k=u&63; BT2[col*64+k] = (f16)W2[(size_t)k*256+col]; return; }
  u -= 16384;
  if (u < 131072){ int j=u>>10, t=u&1023, h=t>>8, k=t&255;
                   BT3[(size_t)j*1024+t] = (f16)W3[(size_t)k*512 + h*128 + j]; return; }
  u -= 131072;
  if (u < 1024){ // PT1[o][k], layer1 block-diagonal: head h owns feats h*16..h*16+15
    int o=u>>6, k=u&63; float v=0.f;
    if (o<8){ int h=o&3; if ((k>>4)==h) v = ((o<4)?as1:ad1)[h*16 + (k&15)]; }
    PT1[u] = (f16)v; return; }
  u -= 1024;
  if (u < 1024){ // PT2[o][k] = sum_c W2[k, h*64+c] * a2_h[c]
    int o=u>>6, k=u&63; float v=0.f;
    if (o<8){ int h=o&3;
      const float* a=((o<4)?as2:ad2)+h*64; const float* w=W2+(size_t)k*256+h*64;
      for(int c=0;c<64;c++) v=fmaf(w[c],a[c],v); }
    PT2[u] = (f16)v; return; }
  u -= 1024;
  if (u < 4096){ // PT3[o][k] = sum_c W3[k, h*128+c] * a3_h[c]
    int o=u>>8, k=u&255; float v=0.f;
    if (o<8){ int h=o&3;
      const float* a=((o<4)?as3:ad3)+h*128; const float* w=W3+(size_t)k*512+h*128;
      for(int c=0;c<128;c++) v=fmaf(w[c],a[c],v); }
    PT3[u] = (f16)v; }
}

__global__ void k_cvt_x(const float* __restrict__ x, f16* __restrict__ xh){
  int u = blockIdx.x*256 + threadIdx.x;
  if (u < NNODES*32){
    float4 v = *(const float4*)&x[(size_t)u*4];
    f16x4 o; o[0]=(f16)v.x; o[1]=(f16)v.y; o[2]=(f16)v.z; o[3]=(f16)v.w;
    *(f16x4*)&xh[(size_t)u*4] = o;
  }
}

// ---------------- scores via MFMA: esd[n][0..3]=es, [4..7]=ed ----------------
template<int KF>
__global__ __launch_bounds__(256) void k_scores_m(const f16* __restrict__ g, const f16* __restrict__ PT,
                                                  float* __restrict__ esd){
  int wv = threadIdx.x>>6, lane = threadIdx.x&63;
  int r = lane&15, kb = lane>>4;
  int row0 = blockIdx.x*64 + wv*16;
  const f16* arow = g + (size_t)(row0+r)*KF + kb*8;
  const f16* brow = PT + (size_t)r*KF + kb*8;
  f32x4 acc = {0,0,0,0};
  #pragma unroll
  for (int k0=0;k0<KF;k0+=32){
    f16x8 af = *(const f16x8*)(arow + k0);
    f16x8 bf = *(const f16x8*)(brow + k0);
    acc = __builtin_amdgcn_mfma_f32_16x16x32_f16(af, bf, acc, 0,0,0);
  }
  if (r < 8){
    #pragma unroll
    for (int i=0;i<4;i++){
      int row = row0 + kb*4 + i;
      if (row < NNODES) esd[(size_t)row*8 + r] = acc[i];
    }
  }
}

// ---------------- edge-parallel softmax numerators: alphaW[p][h] ----------------
__global__ __launch_bounds__(256) void k_expw(const float* __restrict__ esd, const int* __restrict__ csr_src,
                                              const int* __restrict__ csr_dst, float* __restrict__ alphaW){
  int p = blockIdx.x*256 + threadIdx.x;
  if (p >= ETOT) return;
  int s = csr_src[p], d = csr_dst[p];
  float4 a = *(const float4*)&esd[(size_t)s*8];
  float4 b = *(const float4*)&esd[(size_t)d*8+4];
  float4 r;
  r.x = expf(lrelu(a.x+b.x));
  r.y = expf(lrelu(a.y+b.y));
  r.z = expf(lrelu(a.z+b.z));
  r.w = expf(lrelu(a.w+b.w));
  *(float4*)&alphaW[(size_t)p*4] = r;
}

// ---------------- MFMA GEMMs ----------------
// l1: h1[50000,64] = xh[50000,128] @ BT1^T ; raw (no bias/act)
__global__ __launch_bounds__(256) void k_mfma_l1(const f16* __restrict__ xh, const f16* __restrict__ BT1,
                                                 f16* __restrict__ h1h){
  int wv = threadIdx.x>>6, lane = threadIdx.x&63;
  int r = lane&15, kb = lane>>4;
  int row0 = blockIdx.x*64 + wv*16;
  const f16* arow = xh + (size_t)(row0 + r)*128 + kb*8;
  f32x4 acc[4] = {{0,0,0,0},{0,0,0,0},{0,0,0,0},{0,0,0,0}};
  for (int k0=0;k0<128;k0+=32){
    f16x8 af = *(const f16x8*)(arow + k0);
    #pragma unroll
    for (int c=0;c<4;c++){
      f16x8 bf = *(const f16x8*)(BT1 + (size_t)(c*16+r)*128 + k0 + kb*8);
      acc[c] = __builtin_amdgcn_mfma_f32_16x16x32_f16(af, bf, acc[c], 0,0,0);
    }
  }
  #pragma unroll
  for (int c=0;c<4;c++)
    #pragma unroll
    for (int i=0;i<4;i++){
      int row = row0 + kb*4 + i;
      if (row < NNODES) h1h[(size_t)row*64 + c*16 + r] = (f16)acc[c][i];
    }
}

// l2 (per-head): g2[n, h*64+j] = ELU(agg2[n, h*64+:] @ W2_h + b2)
__global__ __launch_bounds__(256) void k_mfma_l2(const f16* __restrict__ agg2h, const f16* __restrict__ BT2,
                                                 const float* __restrict__ b2, f16* __restrict__ g2h){
  int wv = threadIdx.x>>6, lane = threadIdx.x&63;
  int r = lane&15, kb = lane>>4;
  int h = blockIdx.y;
  int row0 = blockIdx.x*64 + wv*16;
  const f16* arow = agg2h + (size_t)(row0 + r)*256 + h*64 + kb*8;
  f32x4 acc[4] = {{0,0,0,0},{0,0,0,0},{0,0,0,0},{0,0,0,0}};
  #pragma unroll
  for (int k0=0;k0<64;k0+=32){
    f16x8 af = *(const f16x8*)(arow + k0);
    #pragma unroll
    for (int c=0;c<4;c++){
      f16x8 bf = *(const f16x8*)(BT2 + (size_t)(h*64+c*16+r)*64 + k0 + kb*8);
      acc[c] = __builtin_amdgcn_mfma_f32_16x16x32_f16(af, bf, acc[c], 0,0,0);
    }
  }
  #pragma unroll
  for (int c=0;c<4;c++){
    int col = h*64 + c*16 + r;
    float bb = b2[col];
    #pragma unroll
    for (int i=0;i<4;i++){
      int row = row0 + kb*4 + i;
      if (row < NNODES) g2h[(size_t)row*256 + col] = (f16)eluf(acc[c][i] + bb);
    }
  }
}

// l3: g3[n,128] = ELU(0.25 * agg3[n,1024] @ BT3^T + b3)
__global__ __launch_bounds__(256) void k_mfma_l3(const f16* __restrict__ agg3h, const f16* __restrict__ BT3,
                                                 const float* __restrict__ b3, float* __restrict__ g3){
  int wv = threadIdx.x>>6, lane = threadIdx.x&63;
  int r = lane&15, kb = lane>>4;
  int row0 = blockIdx.x*128 + wv*32;
  const f16* a0 = agg3h + (size_t)(row0 + r)*1024 + kb*8;
  const f16* a1 = a0 + (size_t)16*1024;
  f32x4 acc[2][8];
  #pragma unroll
  for (int rt=0;rt<2;rt++)
    #pragma unroll
    for (int c=0;c<8;c++) acc[rt][c] = (f32x4){0,0,0,0};
  for (int k0=0;k0<1024;k0+=32){
    f16x8 af0 = *(const f16x8*)(a0 + k0);
    f16x8 af1 = *(const f16x8*)(a1 + k0);
    #pragma unroll
    for (int c=0;c<8;c++){
      f16x8 bf = *(const f16x8*)(BT3 + (size_t)(c*16+r)*1024 + k0 + kb*8);
      acc[0][c] = __builtin_amdgcn_mfma_f32_16x16x32_f16(af0, bf, acc[0][c], 0,0,0);
      acc[1][c] = __builtin_amdgcn_mfma_f32_16x16x32_f16(af1, bf, acc[1][c], 0,0,0);
    }
  }
  #pragma unroll
  for (int rt=0;rt<2;rt++)
    #pragma unroll
    for (int c=0;c<8;c++){
      int col = c*16 + r;
      float bb = b3[col];
      #pragma unroll
      for (int i=0;i<4;i++){
        int row = row0 + rt*16 + kb*4 + i;
        if (row < NNODES) g3[(size_t)row*128 + col] = eluf(0.25f*acc[rt][c][i] + bb);
      }
    }
}

// ---------------- gathers: pure FMA on precomputed alphaW ----------------
__global__ __launch_bounds__(256) void k_gat1f(const f16* __restrict__ h1h, const float* __restrict__ alphaW,
    const int* __restrict__ row_off, const int* __restrict__ csr_src,
    const float* __restrict__ b1, f16* __restrict__ g1h){
  int n = blockIdx.x*4 + (threadIdx.x>>6);
  if (n >= NNODES) return;
  int t = threadIdx.x & 63;
  int head = t >> 4;
  int pos = row_off[n], end = row_off[n+1];
  float acc = 0.f, den = 0.f;
  for (; pos+1 < end; pos += 2){
    int s0 = csr_src[pos], s1 = csr_src[pos+1];
    float w0 = alphaW[(size_t)pos*4 + head];
    float w1 = alphaW[(size_t)(pos+1)*4 + head];
    float v0 = (float)h1h[(size_t)s0*64 + t];
    float v1 = (float)h1h[(size_t)s1*64 + t];
    acc = fmaf(w0, v0, fmaf(w1, v1, acc));
    den += w0 + w1;
  }
  if (pos < end){
    int s0 = csr_src[pos];
    float w0 = alphaW[(size_t)pos*4 + head];
    acc = fmaf(w0, (float)h1h[(size_t)s0*64 + t], acc);
    den += w0;
  }
  g1h[(size_t)n*64 + t] = (f16)eluf(acc/(den + 1e-16f) + b1[t]);
}

__global__ __launch_bounds__(256) void k_agg2f(const f16* __restrict__ g1h, const float* __restrict__ alphaW,
    const int* __restrict__ row_off, const int* __restrict__ csr_src,
    f16* __restrict__ agg2h){
  int n = blockIdx.x*4 + (threadIdx.x>>6);
  if (n >= NNODES) return;
  int t = threadIdx.x & 63;
  int pos = row_off[n], end = row_off[n+1];
  float c0=0.f,c1=0.f,c2=0.f,c3=0.f,d0=0.f,d1=0.f,d2=0.f,d3=0.f;
  for (; pos+1 < end; pos += 2){
    int s0 = csr_src[pos], s1 = csr_src[pos+1];
    float4 a = *(const float4*)&alphaW[(size_t)pos*4];
    float4 b = *(const float4*)&alphaW[(size_t)(pos+1)*4];
    float v0 = (float)g1h[(size_t)s0*64 + t];
    float v1 = (float)g1h[(size_t)s1*64 + t];
    c0=fmaf(a.x,v0,fmaf(b.x,v1,c0)); c1=fmaf(a.y,v0,fmaf(b.y,v1,c1));
    c2=fmaf(a.z,v0,fmaf(b.z,v1,c2)); c3=fmaf(a.w,v0,fmaf(b.w,v1,c3));
    d0+=a.x+b.x; d1+=a.y+b.y; d2+=a.z+b.z; d3+=a.w+b.w;
  }
  if (pos < end){
    int s0 = csr_src[pos];
    float4 a = *(const float4*)&alphaW[(size_t)pos*4];
    float v0 = (float)g1h[(size_t)s0*64 + t];
    c0=fmaf(a.x,v0,c0); c1=fmaf(a.y,v0,c1); c2=fmaf(a.z,v0,c2); c3=fmaf(a.w,v0,c3);
    d0+=a.x; d1+=a.y; d2+=a.z; d3+=a.w;
  }
  size_t base = (size_t)n*256;
  agg2h[base       + t] = (f16)(c0/(d0+1e-16f));
  agg2h[base +  64 + t] = (f16)(c1/(d1+1e-16f));
  agg2h[base + 128 + t] = (f16)(c2/(d2+1e-16f));
  agg2h[base + 192 + t] = (f16)(c3/(d3+1e-16f));
}

__global__ __launch_bounds__(256) void k_agg3f(const f16* __restrict__ g2h, const float* __restrict__ alphaW,
    const int* __restrict__ row_off, const int* __restrict__ csr_src,
    f16* __restrict__ agg3h){
  int n = blockIdx.x*4 + (threadIdx.x>>6);
  if (n >= NNODES) return;
  int lane = threadIdx.x & 63;
  int pos = row_off[n], end = row_off[n+1];
  float acc[4][4] = {};
  float d0=0.f,d1=0.f,d2=0.f,d3=0.f;
  for (; pos+1 < end; pos += 2){
    int s0 = csr_src[pos], s1 = csr_src[pos+1];
    float4 a = *(const float4*)&alphaW[(size_t)pos*4];
    float4 b = *(const float4*)&alphaW[(size_t)(pos+1)*4];
    f16x4 u0 = *(const f16x4*)&g2h[(size_t)s0*256 + lane*4];
    f16x4 u1 = *(const f16x4*)&g2h[(size_t)s1*256 + lane*4];
    float w0[4] = {a.x,a.y,a.z,a.w};
    float w1[4] = {b.x,b.y,b.z,b.w};
    #pragma unroll
    for (int h=0;h<4;h++)
      #pragma unroll
      for (int j=0;j<4;j++)
        acc[h][j] = fmaf(w0[h], (float)u0[j], fmaf(w1[h], (float)u1[j], acc[h][j]));
    d0 += a.x+b.x; d1 += a.y+b.y; d2 += a.z+b.z; d3 += a.w+b.w;
  }
  if (pos < end){
    int s0 = csr_src[pos];
    float4 a = *(const float4*)&alphaW[(size_t)pos*4];
    f16x4 u0 = *(const f16x4*)&g2h[(size_t)s0*256 + lane*4];
    float w0[4] = {a.x,a.y,a.z,a.w};
    #pragma unroll
    for (int h=0;h<4;h++)
      #pragma unroll
      for (int j=0;j<4;j++)
        acc[h][j] = fmaf(w0[h], (float)u0[j], acc[h][j]);
    d0 += a.x; d1 += a.y; d2 += a.z; d3 += a.w;
  }
  float dn[4] = {d0+1e-16f, d1+1e-16f, d2+1e-16f, d3+1e-16f};
  #pragma unroll
  for (int h=0;h<4;h++){
    f16x4 o;
    #pragma unroll
    for (int j=0;j<4;j++) o[j] = (f16)(acc[h][j]/dn[h]);
    *(f16x4*)&agg3h[(size_t)n*1024 + h*256 + lane*4] = o;
  }
}

// ---------------- pooling + linear head ----------------
__device__ __forceinline__ int lowerb(const int* a, int n, int v){
  int lo=0, hi=n;
  while (lo<hi){ int mid=(lo+hi)>>1; if (a[mid]<v) lo=mid+1; else hi=mid; }
  return lo;
}
__global__ void k_pool8(const float* __restrict__ g3, const int* __restrict__ batch, float* __restrict__ pooledS){
  int g = blockIdx.x, ch = blockIdx.y, c = threadIdx.x; // 64 x 8 blocks, 128 threads
  int lo = lowerb(batch, NNODES, g);
  int hi = lowerb(batch, NNODES, g+1);
  int len = hi - lo;
  int b0 = lo + (len*ch)/8, b1 = lo + (len*(ch+1))/8;
  float s = 0.f;
  for (int nn=b0; nn<b1; ++nn) s += g3[(size_t)nn*128 + c];
  if (b1 > b0) atomicAdd(&pooledS[g*128+c], s);
}
__global__ void k_lin(const float* __restrict__ pooledS, const int* __restrict__ batch,
                      const float* __restrict__ Wlin, const float* __restrict__ blin, float* __restrict__ out){
  int t = threadIdx.x;
  if (t < 640){
    int g = t/10, j = t%10;
    int lo = lowerb(batch, NNODES, g);
    int hi = lowerb(batch, NNODES, g+1);
    float inv = 1.f / fmaxf((float)(hi-lo), 1.f);
    float s = blin[j];
    for (int c=0;c<128;c++) s = fmaf(pooledS[g*128+c]*inv, Wlin[c*10+j], s);
    out[t] = s;
  }
}

extern "C" void kernel_launch(void* const* d_in, const int* in_sizes, int n_in,
                              void* d_out, int out_size, void* d_ws, size_t ws_size,
                              hipStream_t stream){
  (void)in_sizes; (void)n_in; (void)out_size; (void)ws_size;
  const float* x    = (const float*)d_in[0];
  const int*   ei   = (const int*)d_in[1];
  const int*   batch= (const int*)d_in[2];
  const float* W1   = (const float*)d_in[3];
  const float* as1  = (const float*)d_in[4];
  const float* ad1  = (const float*)d_in[5];
  const float* b1   = (const float*)d_in[6];
  const float* W2   = (const float*)d_in[7];
  const float* as2  = (const float*)d_in[8];
  const float* ad2  = (const float*)d_in[9];
  const float* b2   = (const float*)d_in[10];
  const float* W3   = (const float*)d_in[11];
  const float* as3  = (const float*)d_in[12];
  const float* ad3  = (const float*)d_in[13];
  const float* b3   = (const float*)d_in[14];
  const float* Wlin = (const float*)d_in[15];
  const float* blin = (const float*)d_in[16];
  float* out = (float*)d_out;

  char* ws = (char*)d_ws;
  size_t off = 0;
  auto alloc = [&](size_t bytes)->char*{ char* p = ws + off; off += (bytes + 255) & ~(size_t)255; return p; };
  int* csr_src = (int*)alloc((size_t)ETOT*4);
  int* csr_dst = (int*)alloc((size_t)ETOT*4);
  int* row_off = (int*)alloc((size_t)(NNODES+1)*4);
  int* deg     = (int*)alloc((size_t)NNODES*4);
  int* cursor  = (int*)alloc((size_t)NNODES*4);
  int* part    = (int*)alloc(256*4);
  int* bpre    = (int*)alloc(256*4);
  float* esd   = (float*)alloc((size_t)NNODES*8*4);
  float* alphaW= (float*)alloc((size_t)ETOT*4*4);     // 7.2 MB
  f16* BT1     = (f16*)alloc(8192*2);
  f16* BT2     = (f16*)alloc(16384*2);
  f16* BT3     = (f16*)alloc(131072*2);
  f16* PT1     = (f16*)alloc(1024*2);
  f16* PT2     = (f16*)alloc(1024*2);
  f16* PT3     = (f16*)alloc(4096*2);
  float* pooledS = (float*)alloc((size_t)NGRAPHS*128*4);
  f16* xh      = (f16*)alloc((size_t)NNODES*128*2);   // 12.8 MB
  f16* h1h     = (f16*)alloc((size_t)NNODES*64*2);    //  6.4 MB (absorbs OOB-read tails)
  f16* g1h     = (f16*)alloc((size_t)NNODES*64*2);    //  6.4 MB
  f16* agg2h   = (f16*)alloc((size_t)NNODES*256*2);   // 25.6 MB
  f16* g2h     = (f16*)alloc((size_t)NNODES*256*2);   // 25.6 MB
  f16* agg3h   = (f16*)alloc((size_t)NNODES*1024*2);  // 102.4 MB
  float* g3    = (float*)alloc((size_t)NNODES*128*4); // 25.6 MB

  int nbE = (NEDGES+255)/256;
  int nbS = (NNODES+255)/256;
  int nbP = (ETOT+255)/256;
  int nb4 = (NNODES+3)/4;

  // CSR with self-loop at slot 0 of each row
  k_one<<<nbS,256,0,stream>>>(deg);
  k_hist<<<nbE,256,0,stream>>>(ei, deg);
  k_scan1<<<nbS,256,0,stream>>>(deg, part, NNODES);
  k_scan2<<<1,256,0,stream>>>(part, bpre, row_off+NNODES, nbS);
  k_scan3<<<nbS,256,0,stream>>>(deg, bpre, row_off, NNODES);
  k_selfpos<<<nbS,256,0,stream>>>(row_off, csr_src, csr_dst, cursor);
  k_scatter<<<nbE,256,0,stream>>>(ei, row_off, cursor, csr_src, csr_dst);

  // weight prep + x cast
  k_prep<<<632,256,0,stream>>>(W1,W2,W3,as1,ad1,as2,ad2,as3,ad3,BT1,BT2,BT3,PT1,PT2,PT3);
  k_cvt_x<<<6250,256,0,stream>>>(x, xh);

  // layer 1
  k_mfma_l1<<<782,256,0,stream>>>(xh, BT1, h1h);
  k_scores_m<64><<<782,256,0,stream>>>(h1h, PT1, esd);
  k_expw<<<nbP,256,0,stream>>>(esd, csr_src, csr_dst, alphaW);
  k_gat1f<<<nb4,256,0,stream>>>(h1h, alphaW, row_off, csr_src, b1, g1h);

  // layer 2
  k_scores_m<64><<<782,256,0,stream>>>(g1h, PT2, esd);
  k_expw<<<nbP,256,0,stream>>>(esd, csr_src, csr_dst, alphaW);
  k_agg2f<<<nb4,256,0,stream>>>(g1h, alphaW, row_off, csr_src, agg2h);
  k_mfma_l2<<<dim3(782,4),256,0,stream>>>(agg2h, BT2, b2, g2h);

  // layer 3
  k_scores_m<256><<<782,256,0,stream>>>(g2h, PT3, esd);
  k_expw<<<nbP,256,0,stream>>>(esd, csr_src, csr_dst, alphaW);
  k_agg3f<<<nb4,256,0,stream>>>(g2h, alphaW, row_off, csr_src, agg3h);
  k_mfma_l3<<<391,256,0,stream>>>(agg3h, BT3, b3, g3);

  // pool + linear
  hipMemsetAsync(pooledS, 0, (size_t)NGRAPHS*128*4, stream);
  k_pool8<<<dim3(NGRAPHS,8),128,0,stream>>>(g3, batch, pooledS);
  k_lin<<<1,1024,0,stream>>>(pooledS, batch, Wlin, blin, out);
}